// Round 1
// baseline (1033.044 us; speedup 1.0000x reference)
//
#include <hip/hip_runtime.h>
#include <hip/hip_bf16.h>
#include <cstdint>

// ---------------------------------------------------------------------------
// DynamicGAT: GraphConv(2->64) + GAT(64->4x64) + GAT(256->4x64) + GAT(256->64)
// N=50000 nodes, E=800000 edges (+N self loops for GAT layers).
// Strategy: CSR-by-dst build once per call; per-layer fp32 GEMM (h@W);
// per-node gather kernel with online softmax (no float scatter atomics).
// ---------------------------------------------------------------------------

// ---------------- CSR build ----------------
__global__ void count_kernel(const int* __restrict__ dst, int E, int N,
                             int* __restrict__ counts) {
  int e = blockIdx.x * blockDim.x + threadIdx.x;
  if (e >= E + N) return;
  int d = (e < E) ? dst[e] : (e - E);   // self loops appended
  atomicAdd(&counts[d], 1);
}

__global__ void scan_kernel(const int* __restrict__ counts, int* __restrict__ rowptr,
                            int* __restrict__ cursor, int n) {
  __shared__ int lds[1024];
  __shared__ int carry;
  int t = threadIdx.x;
  if (t == 0) { carry = 0; rowptr[0] = 0; }
  __syncthreads();
  for (int base = 0; base < n; base += 1024) {
    int i = base + t;
    int v = (i < n) ? counts[i] : 0;
    lds[t] = v;
    __syncthreads();
    for (int off = 1; off < 1024; off <<= 1) {
      int x = lds[t];
      if (t >= off) x += lds[t - off];
      __syncthreads();
      lds[t] = x;
      __syncthreads();
    }
    int incl = lds[t];
    int tot = lds[1023];
    int c = carry;
    if (i < n) {
      rowptr[i + 1] = c + incl;      // inclusive -> rowptr shifted by one
      cursor[i] = c + incl - v;      // exclusive prefix = row start
    }
    __syncthreads();
    if (t == 0) carry = c + tot;
    __syncthreads();
  }
}

__global__ void scatter_kernel(const int* __restrict__ src, const int* __restrict__ dst,
                               int E, int N, int* __restrict__ cursor,
                               int* __restrict__ adj) {
  int e = blockIdx.x * blockDim.x + threadIdx.x;
  if (e >= E + N) return;
  int s, d;
  if (e < E) { s = src[e]; d = dst[e]; }
  else       { s = e - E; d = s; }
  int slot = atomicAdd(&cursor[d], 1);
  adj[slot] = s;   // store src only; alpha recomputable from (src, dst=row)
}

// ---------------- GraphConv ----------------
__global__ void agg_kernel(const float* __restrict__ x, const int* __restrict__ src,
                           const int* __restrict__ dst, int E, float* __restrict__ agg) {
  int e = blockIdx.x * blockDim.x + threadIdx.x;
  if (e >= E) return;
  int s = src[e], d = dst[e];
  atomicAdd(&agg[d * 2 + 0], x[s * 2 + 0]);
  atomicAdd(&agg[d * 2 + 1], x[s * 2 + 1]);
}

__global__ void graphconv_kernel(const float* __restrict__ x, const float* __restrict__ agg,
                                 const float* __restrict__ W_rel, const float* __restrict__ b_rel,
                                 const float* __restrict__ W_root, float* __restrict__ h0,
                                 int Nn) {
  int i = blockIdx.x * blockDim.x + threadIdx.x;
  if (i >= Nn * 64) return;
  int n = i >> 6, c = i & 63;
  float a0 = agg[n * 2], a1 = agg[n * 2 + 1];
  float x0 = x[n * 2], x1 = x[n * 2 + 1];
  float v = a0 * W_rel[c] + a1 * W_rel[64 + c]
          + x0 * W_root[c] + x1 * W_root[64 + c] + b_rel[c];
  h0[i] = fmaxf(v, 0.f);
}

// ---------------- fp32 tiled GEMM: C[M,N] = A[M,K] @ B[K,N] ----------------
#define GBM 128
#define GBN 64
#define GBK 16
#define GTM 8
#define GTN 4

__global__ __launch_bounds__(256) void sgemm_kernel(const float* __restrict__ A,
    const float* __restrict__ B, float* __restrict__ C, int M, int N, int K) {
  __shared__ float As[GBK][GBM + 4];   // +4 pad: conflict-free + 16B-aligned rows
  __shared__ float Bs[GBK][GBN];
  int t = threadIdx.x;
  int tx = t & 15, ty = t >> 4;
  int row0 = blockIdx.y * GBM;
  int col0 = blockIdx.x * GBN;
  float acc[GTM][GTN] = {};
  for (int k0 = 0; k0 < K; k0 += GBK) {
#pragma unroll
    for (int i = t; i < GBM * GBK; i += 256) {
      int m = i >> 4, kk = i & 15;
      int r = row0 + m;
      As[kk][m] = (r < M) ? A[(size_t)r * K + k0 + kk] : 0.f;
    }
#pragma unroll
    for (int i = t; i < GBK * GBN; i += 256) {
      int kk = i >> 6, nn = i & 63;
      Bs[kk][nn] = B[(size_t)(k0 + kk) * N + col0 + nn];
    }
    __syncthreads();
#pragma unroll
    for (int kk = 0; kk < GBK; ++kk) {
      float a[GTM], b[GTN];
#pragma unroll
      for (int im = 0; im < GTM; ++im) a[im] = As[kk][ty * GTM + im];
#pragma unroll
      for (int in = 0; in < GTN; ++in) b[in] = Bs[kk][tx * GTN + in];
#pragma unroll
      for (int im = 0; im < GTM; ++im)
#pragma unroll
        for (int in = 0; in < GTN; ++in) acc[im][in] += a[im] * b[in];
    }
    __syncthreads();
  }
#pragma unroll
  for (int im = 0; im < GTM; ++im) {
    int r = row0 + ty * GTM + im;
    if (r < M) {
#pragma unroll
      for (int in = 0; in < GTN; ++in)
        C[(size_t)r * N + col0 + tx * GTN + in] = acc[im][in];
    }
  }
}

// ---------------- per-node attention logits al_s/al_d ----------------
template <int HC>
__global__ __launch_bounds__(HC) void al_kernel(const float* __restrict__ hW,
    const float* __restrict__ a_s, const float* __restrict__ a_d,
    float* __restrict__ alS, float* __restrict__ alD) {
  constexpr int H = HC / 64;
  int node = blockIdx.x, t = threadIdx.x;
  float v = hW[(size_t)node * HC + t];
  float ps = v * a_s[t];
  float pd = v * a_d[t];
#pragma unroll
  for (int off = 32; off; off >>= 1) {
    ps += __shfl_down(ps, off);
    pd += __shfl_down(pd, off);
  }
  if ((t & 63) == 0) {
    alS[node * H + (t >> 6)] = ps;
    alD[node * H + (t >> 6)] = pd;
  }
}

// ---------------- GAT gather with online softmax ----------------
// block = one dst node; HC threads; wave w == head w (C=64).
template <int HC, bool RELU>
__global__ __launch_bounds__(HC) void gat_gather(const float* __restrict__ hW,
    const float* __restrict__ alS, const float* __restrict__ alD,
    const int* __restrict__ rowptr, const int* __restrict__ adj,
    const float* __restrict__ bias, float* __restrict__ out) {
  constexpr int H = HC / 64;
  int node = blockIdx.x;
  int t = threadIdx.x;
  int head = t >> 6;
  float ald = alD[node * H + head];
  int s0 = rowptr[node], s1 = rowptr[node + 1];
  float m = -3.0e38f, den = 0.f, acc = 0.f;
  for (int s = s0; s < s1; ++s) {
    int src = adj[s];
    float v = alS[src * H + head] + ald;
    v = v > 0.f ? v : 0.2f * v;            // leaky_relu(0.2)
    if (v > m) {                            // wave-uniform branch
      float r = __expf(m - v);
      acc *= r; den *= r; m = v;
    }
    float w = __expf(v - m);
    den += w;
    acc += w * hW[(size_t)src * HC + t];    // 256B/wave coalesced gather
  }
  float o = acc / (den + 1e-16f) + bias[t];
  if (RELU) o = fmaxf(o, 0.f);
  out[(size_t)node * HC + t] = o;
}

// ---------------------------------------------------------------------------
extern "C" void kernel_launch(void* const* d_in, const int* in_sizes, int n_in,
                              void* d_out, int out_size, void* d_ws, size_t ws_size,
                              hipStream_t stream) {
  const float* x      = (const float*)d_in[0];
  const float* W_rel  = (const float*)d_in[1];
  const float* b_rel  = (const float*)d_in[2];
  const float* W_root = (const float*)d_in[3];
  const float* W1     = (const float*)d_in[4];
  const float* a_s1   = (const float*)d_in[5];
  const float* a_d1   = (const float*)d_in[6];
  const float* b1     = (const float*)d_in[7];
  const float* W2     = (const float*)d_in[8];
  const float* a_s2   = (const float*)d_in[9];
  const float* a_d2   = (const float*)d_in[10];
  const float* b2     = (const float*)d_in[11];
  const float* W3     = (const float*)d_in[12];
  const float* a_s3   = (const float*)d_in[13];
  const float* a_d3   = (const float*)d_in[14];
  const float* b3     = (const float*)d_in[15];
  const int*   ei     = (const int*)d_in[16];

  int N = in_sizes[0] / 2;
  int E = in_sizes[16] / 2;
  const int* srcp = ei;
  const int* dstp = ei + E;

  // workspace layout (~121 MB)
  float* ws   = (float*)d_ws;
  float* agg  = ws;                          // N*2
  float* h0   = agg + (size_t)N * 2;         // N*64
  float* bufA = h0 + (size_t)N * 64;         // N*256  (hW1 / hW2 / hW3)
  float* bufB = bufA + (size_t)N * 256;      // N*256  (h1 / h2)
  float* alS  = bufB + (size_t)N * 256;      // N*4
  float* alD  = alS + (size_t)N * 4;         // N*4
  int* rowptr = (int*)(alD + (size_t)N * 4); // N+1
  int* counts = rowptr + (N + 1);            // N
  int* cursor = counts + N;                  // N
  int* adj    = cursor + N;                  // E+N

  hipMemsetAsync(agg, 0, (size_t)N * 2 * sizeof(float), stream);
  hipMemsetAsync(counts, 0, (size_t)N * sizeof(int), stream);

  int ESL = E + N;
  int tb = 256;

  // CSR build (same adjacency for all 3 GAT layers)
  count_kernel<<<(ESL + tb - 1) / tb, tb, 0, stream>>>(dstp, E, N, counts);
  scan_kernel<<<1, 1024, 0, stream>>>(counts, rowptr, cursor, N);
  scatter_kernel<<<(ESL + tb - 1) / tb, tb, 0, stream>>>(srcp, dstp, E, N, cursor, adj);

  // GraphConv (real edges only) + ReLU
  agg_kernel<<<(E + tb - 1) / tb, tb, 0, stream>>>(x, srcp, dstp, E, agg);
  graphconv_kernel<<<(N * 64 + tb - 1) / tb, tb, 0, stream>>>(x, agg, W_rel, b_rel, W_root, h0, N);

  dim3 g1(256 / GBN, (N + GBM - 1) / GBM);
  dim3 g3(64 / GBN, (N + GBM - 1) / GBM);

  // GAT layer 1: 64 -> 4x64, relu
  sgemm_kernel<<<g1, 256, 0, stream>>>(h0, W1, bufA, N, 256, 64);
  al_kernel<256><<<N, 256, 0, stream>>>(bufA, a_s1, a_d1, alS, alD);
  gat_gather<256, true><<<N, 256, 0, stream>>>(bufA, alS, alD, rowptr, adj, b1, bufB);

  // GAT layer 2: 256 -> 4x64, relu
  sgemm_kernel<<<g1, 256, 0, stream>>>(bufB, W2, bufA, N, 256, 256);
  al_kernel<256><<<N, 256, 0, stream>>>(bufA, a_s2, a_d2, alS, alD);
  gat_gather<256, true><<<N, 256, 0, stream>>>(bufA, alS, alD, rowptr, adj, b2, bufB);

  // GAT layer 3: 256 -> 64, heads=1, no relu
  sgemm_kernel<<<g3, 256, 0, stream>>>(bufB, W3, bufA, N, 64, 256);
  al_kernel<64><<<N, 64, 0, stream>>>(bufA, a_s3, a_d3, alS, alD);
  gat_gather<64, false><<<N, 64, 0, stream>>>(bufA, alS, alD, rowptr, adj, b3, (float*)d_out);
}

// Round 2
// 871.345 us; speedup vs baseline: 1.1856x; 1.1856x over previous
//
#include <hip/hip_runtime.h>
#include <hip/hip_bf16.h>
#include <cstdint>

// ---------------------------------------------------------------------------
// DynamicGAT: GraphConv(2->64) + GAT(64->4x64) + GAT(256->4x64) + GAT(256->64)
// N=50000 nodes, E=800000 edges (+N self loops for GAT layers).
// R1: gather restructured — 1 wave = 1 edge (float4/lane), 4 edges in flight
// per block, online-softmax partials merged once per node (LDS / shfl).
// ---------------------------------------------------------------------------

// ---------------- CSR build ----------------
__global__ void count_kernel(const int* __restrict__ dst, int E, int N,
                             int* __restrict__ counts) {
  int e = blockIdx.x * blockDim.x + threadIdx.x;
  if (e >= E + N) return;
  int d = (e < E) ? dst[e] : (e - E);   // self loops appended
  atomicAdd(&counts[d], 1);
}

__global__ void scan_kernel(const int* __restrict__ counts, int* __restrict__ rowptr,
                            int* __restrict__ cursor, int n) {
  __shared__ int lds[1024];
  __shared__ int carry;
  int t = threadIdx.x;
  if (t == 0) { carry = 0; rowptr[0] = 0; }
  __syncthreads();
  for (int base = 0; base < n; base += 1024) {
    int i = base + t;
    int v = (i < n) ? counts[i] : 0;
    lds[t] = v;
    __syncthreads();
    for (int off = 1; off < 1024; off <<= 1) {
      int x = lds[t];
      if (t >= off) x += lds[t - off];
      __syncthreads();
      lds[t] = x;
      __syncthreads();
    }
    int incl = lds[t];
    int tot = lds[1023];
    int c = carry;
    if (i < n) {
      rowptr[i + 1] = c + incl;      // inclusive -> rowptr shifted by one
      cursor[i] = c + incl - v;      // exclusive prefix = row start
    }
    __syncthreads();
    if (t == 0) carry = c + tot;
    __syncthreads();
  }
}

__global__ void scatter_kernel(const int* __restrict__ src, const int* __restrict__ dst,
                               int E, int N, int* __restrict__ cursor,
                               int* __restrict__ adj) {
  int e = blockIdx.x * blockDim.x + threadIdx.x;
  if (e >= E + N) return;
  int s, d;
  if (e < E) { s = src[e]; d = dst[e]; }
  else       { s = e - E; d = s; }
  int slot = atomicAdd(&cursor[d], 1);
  adj[slot] = s;
}

// ---------------- GraphConv ----------------
__global__ void agg_kernel(const float* __restrict__ x, const int* __restrict__ src,
                           const int* __restrict__ dst, int E, float* __restrict__ agg) {
  int e = blockIdx.x * blockDim.x + threadIdx.x;
  if (e >= E) return;
  int s = src[e], d = dst[e];
  atomicAdd(&agg[d * 2 + 0], x[s * 2 + 0]);
  atomicAdd(&agg[d * 2 + 1], x[s * 2 + 1]);
}

__global__ void graphconv_kernel(const float* __restrict__ x, const float* __restrict__ agg,
                                 const float* __restrict__ W_rel, const float* __restrict__ b_rel,
                                 const float* __restrict__ W_root, float* __restrict__ h0,
                                 int Nn) {
  int i = blockIdx.x * blockDim.x + threadIdx.x;
  if (i >= Nn * 64) return;
  int n = i >> 6, c = i & 63;
  float a0 = agg[n * 2], a1 = agg[n * 2 + 1];
  float x0 = x[n * 2], x1 = x[n * 2 + 1];
  float v = a0 * W_rel[c] + a1 * W_rel[64 + c]
          + x0 * W_root[c] + x1 * W_root[64 + c] + b_rel[c];
  h0[i] = fmaxf(v, 0.f);
}

// ---------------- fp32 tiled GEMM: C[M,N] = A[M,K] @ B[K,N] ----------------
#define GBM 128
#define GBN 64
#define GBK 16
#define GTM 8
#define GTN 4

__global__ __launch_bounds__(256) void sgemm_kernel(const float* __restrict__ A,
    const float* __restrict__ B, float* __restrict__ C, int M, int N, int K) {
  __shared__ float As[GBK][GBM + 4];
  __shared__ float Bs[GBK][GBN];
  int t = threadIdx.x;
  int tx = t & 15, ty = t >> 4;
  int row0 = blockIdx.y * GBM;
  int col0 = blockIdx.x * GBN;
  float acc[GTM][GTN] = {};
  for (int k0 = 0; k0 < K; k0 += GBK) {
#pragma unroll
    for (int i = t; i < GBM * GBK; i += 256) {
      int m = i >> 4, kk = i & 15;
      int r = row0 + m;
      As[kk][m] = (r < M) ? A[(size_t)r * K + k0 + kk] : 0.f;
    }
#pragma unroll
    for (int i = t; i < GBK * GBN; i += 256) {
      int kk = i >> 6, nn = i & 63;
      Bs[kk][nn] = B[(size_t)(k0 + kk) * N + col0 + nn];
    }
    __syncthreads();
#pragma unroll
    for (int kk = 0; kk < GBK; ++kk) {
      float a[GTM], b[GTN];
#pragma unroll
      for (int im = 0; im < GTM; ++im) a[im] = As[kk][ty * GTM + im];
#pragma unroll
      for (int in = 0; in < GTN; ++in) b[in] = Bs[kk][tx * GTN + in];
#pragma unroll
      for (int im = 0; im < GTM; ++im)
#pragma unroll
        for (int in = 0; in < GTN; ++in) acc[im][in] += a[im] * b[in];
    }
    __syncthreads();
  }
#pragma unroll
  for (int im = 0; im < GTM; ++im) {
    int r = row0 + ty * GTM + im;
    if (r < M) {
#pragma unroll
      for (int in = 0; in < GTN; ++in)
        C[(size_t)r * N + col0 + tx * GTN + in] = acc[im][in];
    }
  }
}

// ---------------- per-node attention logits al_s/al_d ----------------
template <int HC>
__global__ __launch_bounds__(HC) void al_kernel(const float* __restrict__ hW,
    const float* __restrict__ a_s, const float* __restrict__ a_d,
    float* __restrict__ alS, float* __restrict__ alD) {
  constexpr int H = HC / 64;
  int node = blockIdx.x, t = threadIdx.x;
  float v = hW[(size_t)node * HC + t];
  float ps = v * a_s[t];
  float pd = v * a_d[t];
#pragma unroll
  for (int off = 32; off; off >>= 1) {
    ps += __shfl_down(ps, off);
    pd += __shfl_down(pd, off);
  }
  if ((t & 63) == 0) {
    alS[node * H + (t >> 6)] = ps;
    alD[node * H + (t >> 6)] = pd;
  }
}

// ---------------- GAT gather, 256 channels (4 heads) ----------------
// block = 1 node, 4 waves. Each wave owns one edge per iteration and covers
// the full 256-float row: lane l -> channels [4l,4l+4), head = l>>4.
// Per-wave online softmax (m, den, acc4); LDS merge of the 4 partials.
template <bool RELU>
__global__ __launch_bounds__(256) void gat_gather256(const float* __restrict__ hW,
    const float* __restrict__ alS, const float* __restrict__ alD,
    const int* __restrict__ rowptr, const int* __restrict__ adj,
    const float* __restrict__ bias, float* __restrict__ out) {
  __shared__ float sAcc[4][256];
  __shared__ float sM[4][4];
  __shared__ float sDen[4][4];
  int node = blockIdx.x;
  int t = threadIdx.x;
  int w = t >> 6, l = t & 63;
  int head = l >> 4;
  int c = l << 2;
  float ald = alD[node * 4 + head];
  int s0 = rowptr[node], s1 = rowptr[node + 1];
  float m = -3.0e38f, den = 0.f;
  float ax = 0.f, ay = 0.f, az = 0.f, aw = 0.f;
  for (int s = s0 + w; s < s1; s += 4) {
    int src = adj[s];
    float v = alS[src * 4 + head] + ald;
    v = v > 0.f ? v : 0.2f * v;                  // leaky_relu(0.2)
    float mn = fmaxf(m, v);
    float sc = __expf(m - mn);
    float wt = __expf(v - mn);
    m = mn;
    const float4 hv = *reinterpret_cast<const float4*>(hW + (size_t)src * 256 + c);
    den = den * sc + wt;
    ax = ax * sc + wt * hv.x;
    ay = ay * sc + wt * hv.y;
    az = az * sc + wt * hv.z;
    aw = aw * sc + wt * hv.w;
  }
  if ((l & 15) == 0) { sM[w][head] = m; sDen[w][head] = den; }
  *reinterpret_cast<float4*>(&sAcc[w][c]) = make_float4(ax, ay, az, aw);
  __syncthreads();
  float m0 = sM[0][head], m1 = sM[1][head], m2 = sM[2][head], m3 = sM[3][head];
  float M = fmaxf(fmaxf(m0, m1), fmaxf(m2, m3));
  float dtot = 0.f, bx = 0.f, by = 0.f, bz = 0.f, bw = 0.f;
#pragma unroll
  for (int ww = 0; ww < 4; ++ww) {
    float sc = __expf(sM[ww][head] - M);
    dtot += sDen[ww][head] * sc;
    const float4 av = *reinterpret_cast<const float4*>(&sAcc[ww][c]);
    bx += av.x * sc; by += av.y * sc; bz += av.z * sc; bw += av.w * sc;
  }
  if (w == 0) {
    float inv = 1.f / (dtot + 1e-16f);
    float o0 = bx * inv + bias[c + 0];
    float o1 = by * inv + bias[c + 1];
    float o2 = bz * inv + bias[c + 2];
    float o3 = bw * inv + bias[c + 3];
    if (RELU) {
      o0 = fmaxf(o0, 0.f); o1 = fmaxf(o1, 0.f);
      o2 = fmaxf(o2, 0.f); o3 = fmaxf(o3, 0.f);
    }
    *reinterpret_cast<float4*>(out + (size_t)node * 256 + c) = make_float4(o0, o1, o2, o3);
  }
}

// ---------------- GAT gather, 64 channels (1 head) ----------------
// block = 256 threads = 4 nodes (1 wave each). Within a wave: 4 groups of 16
// lanes; group g owns edge s0+g+4k; lane covers channels [(l&15)*4, +4).
// Merge the 4 group partials via shfl_xor(16), shfl_xor(32).
template <bool RELU>
__global__ __launch_bounds__(256) void gat_gather64(const float* __restrict__ hW,
    const float* __restrict__ alS, const float* __restrict__ alD,
    const int* __restrict__ rowptr, const int* __restrict__ adj,
    const float* __restrict__ bias, float* __restrict__ out, int N) {
  int w = threadIdx.x >> 6, l = threadIdx.x & 63;
  int node = blockIdx.x * 4 + w;
  if (node >= N) return;
  int g = l >> 4;
  int c = (l & 15) << 2;
  float ald = alD[node];
  int s0 = rowptr[node], s1 = rowptr[node + 1];
  float m = -3.0e38f, den = 0.f;
  float ax = 0.f, ay = 0.f, az = 0.f, aw = 0.f;
  for (int s = s0 + g; s < s1; s += 4) {
    int src = adj[s];
    float v = alS[src] + ald;
    v = v > 0.f ? v : 0.2f * v;
    float mn = fmaxf(m, v);
    float sc = __expf(m - mn);
    float wt = __expf(v - mn);
    m = mn;
    const float4 hv = *reinterpret_cast<const float4*>(hW + (size_t)src * 64 + c);
    den = den * sc + wt;
    ax = ax * sc + wt * hv.x;
    ay = ay * sc + wt * hv.y;
    az = az * sc + wt * hv.z;
    aw = aw * sc + wt * hv.w;
  }
#pragma unroll
  for (int off = 16; off <= 32; off <<= 1) {
    float mo = __shfl_xor(m, off);
    float dn = __shfl_xor(den, off);
    float ox = __shfl_xor(ax, off), oy = __shfl_xor(ay, off);
    float oz = __shfl_xor(az, off), ow = __shfl_xor(aw, off);
    float M = fmaxf(m, mo);
    float sa = __expf(m - M), sb = __expf(mo - M);
    m = M;
    den = den * sa + dn * sb;
    ax = ax * sa + ox * sb; ay = ay * sa + oy * sb;
    az = az * sa + oz * sb; aw = aw * sa + ow * sb;
  }
  if (g == 0) {
    float inv = 1.f / (den + 1e-16f);
    float o0 = ax * inv + bias[c + 0];
    float o1 = ay * inv + bias[c + 1];
    float o2 = az * inv + bias[c + 2];
    float o3 = aw * inv + bias[c + 3];
    if (RELU) {
      o0 = fmaxf(o0, 0.f); o1 = fmaxf(o1, 0.f);
      o2 = fmaxf(o2, 0.f); o3 = fmaxf(o3, 0.f);
    }
    *reinterpret_cast<float4*>(out + (size_t)node * 64 + c) = make_float4(o0, o1, o2, o3);
  }
}

// ---------------------------------------------------------------------------
extern "C" void kernel_launch(void* const* d_in, const int* in_sizes, int n_in,
                              void* d_out, int out_size, void* d_ws, size_t ws_size,
                              hipStream_t stream) {
  const float* x      = (const float*)d_in[0];
  const float* W_rel  = (const float*)d_in[1];
  const float* b_rel  = (const float*)d_in[2];
  const float* W_root = (const float*)d_in[3];
  const float* W1     = (const float*)d_in[4];
  const float* a_s1   = (const float*)d_in[5];
  const float* a_d1   = (const float*)d_in[6];
  const float* b1     = (const float*)d_in[7];
  const float* W2     = (const float*)d_in[8];
  const float* a_s2   = (const float*)d_in[9];
  const float* a_d2   = (const float*)d_in[10];
  const float* b2     = (const float*)d_in[11];
  const float* W3     = (const float*)d_in[12];
  const float* a_s3   = (const float*)d_in[13];
  const float* a_d3   = (const float*)d_in[14];
  const float* b3     = (const float*)d_in[15];
  const int*   ei     = (const int*)d_in[16];

  int N = in_sizes[0] / 2;
  int E = in_sizes[16] / 2;
  const int* srcp = ei;
  const int* dstp = ei + E;

  // workspace layout (~121 MB)
  float* ws   = (float*)d_ws;
  float* agg  = ws;                          // N*2
  float* h0   = agg + (size_t)N * 2;         // N*64
  float* bufA = h0 + (size_t)N * 64;         // N*256  (hW1 / hW2 / hW3)
  float* bufB = bufA + (size_t)N * 256;      // N*256  (h1 / h2)
  float* alS  = bufB + (size_t)N * 256;      // N*4
  float* alD  = alS + (size_t)N * 4;         // N*4
  int* rowptr = (int*)(alD + (size_t)N * 4); // N+1
  int* counts = rowptr + (N + 1);            // N
  int* cursor = counts + N;                  // N
  int* adj    = cursor + N;                  // E+N

  hipMemsetAsync(agg, 0, (size_t)N * 2 * sizeof(float), stream);
  hipMemsetAsync(counts, 0, (size_t)N * sizeof(int), stream);

  int ESL = E + N;
  int tb = 256;

  // CSR build (same adjacency for all 3 GAT layers)
  count_kernel<<<(ESL + tb - 1) / tb, tb, 0, stream>>>(dstp, E, N, counts);
  scan_kernel<<<1, 1024, 0, stream>>>(counts, rowptr, cursor, N);
  scatter_kernel<<<(ESL + tb - 1) / tb, tb, 0, stream>>>(srcp, dstp, E, N, cursor, adj);

  // GraphConv (real edges only) + ReLU
  agg_kernel<<<(E + tb - 1) / tb, tb, 0, stream>>>(x, srcp, dstp, E, agg);
  graphconv_kernel<<<(N * 64 + tb - 1) / tb, tb, 0, stream>>>(x, agg, W_rel, b_rel, W_root, h0, N);

  dim3 g1(256 / GBN, (N + GBM - 1) / GBM);
  dim3 g3(64 / GBN, (N + GBM - 1) / GBM);

  // GAT layer 1: 64 -> 4x64, relu
  sgemm_kernel<<<g1, 256, 0, stream>>>(h0, W1, bufA, N, 256, 64);
  al_kernel<256><<<N, 256, 0, stream>>>(bufA, a_s1, a_d1, alS, alD);
  gat_gather256<true><<<N, 256, 0, stream>>>(bufA, alS, alD, rowptr, adj, b1, bufB);

  // GAT layer 2: 256 -> 4x64, relu
  sgemm_kernel<<<g1, 256, 0, stream>>>(bufB, W2, bufA, N, 256, 256);
  al_kernel<256><<<N, 256, 0, stream>>>(bufA, a_s2, a_d2, alS, alD);
  gat_gather256<true><<<N, 256, 0, stream>>>(bufA, alS, alD, rowptr, adj, b2, bufB);

  // GAT layer 3: 256 -> 64, heads=1, no relu
  sgemm_kernel<<<g3, 256, 0, stream>>>(bufB, W3, bufA, N, 64, 256);
  al_kernel<64><<<N, 64, 0, stream>>>(bufA, a_s3, a_d3, alS, alD);
  gat_gather64<false><<<(N + 3) / 4, 256, 0, stream>>>(bufA, alS, alD, rowptr, adj, b3, (float*)d_out, N);
}

// Round 3
// 695.494 us; speedup vs baseline: 1.4853x; 1.2528x over previous
//
#include <hip/hip_runtime.h>
#include <hip/hip_bf16.h>
#include <cstdint>

// ---------------------------------------------------------------------------
// DynamicGAT: GraphConv(2->64) + GAT(64->4x64) + GAT(256->4x64) + GAT(256->64)
// R2: GEMMs moved to bf16 MFMA (16x16x32), fp32 accum. GEMM inputs produced
// directly in bf16 by upstream kernels; weights pre-transposed to bf16 Wt[N][K].
// Attention/softmax path remains fp32.
// ---------------------------------------------------------------------------

typedef __attribute__((ext_vector_type(8))) short bf16x8;
typedef __attribute__((ext_vector_type(4))) float f32x4;

__device__ inline unsigned short f2bf(float f) {
  union { float f; uint32_t u; } x; x.f = f;
  uint32_t r = x.u + 0x7FFF + ((x.u >> 16) & 1);   // RNE
  return (unsigned short)(r >> 16);
}

// ---------------- CSR build ----------------
__global__ void count_kernel(const int* __restrict__ dst, int E, int N,
                             int* __restrict__ counts) {
  int e = blockIdx.x * blockDim.x + threadIdx.x;
  if (e >= E + N) return;
  int d = (e < E) ? dst[e] : (e - E);   // self loops appended
  atomicAdd(&counts[d], 1);
}

__global__ void scan_kernel(const int* __restrict__ counts, int* __restrict__ rowptr,
                            int* __restrict__ cursor, int n) {
  __shared__ int lds[1024];
  __shared__ int carry;
  int t = threadIdx.x;
  if (t == 0) { carry = 0; rowptr[0] = 0; }
  __syncthreads();
  for (int base = 0; base < n; base += 1024) {
    int i = base + t;
    int v = (i < n) ? counts[i] : 0;
    lds[t] = v;
    __syncthreads();
    for (int off = 1; off < 1024; off <<= 1) {
      int x = lds[t];
      if (t >= off) x += lds[t - off];
      __syncthreads();
      lds[t] = x;
      __syncthreads();
    }
    int incl = lds[t];
    int tot = lds[1023];
    int c = carry;
    if (i < n) {
      rowptr[i + 1] = c + incl;
      cursor[i] = c + incl - v;
    }
    __syncthreads();
    if (t == 0) carry = c + tot;
    __syncthreads();
  }
}

__global__ void scatter_kernel(const int* __restrict__ src, const int* __restrict__ dst,
                               int E, int N, int* __restrict__ cursor,
                               int* __restrict__ adj) {
  int e = blockIdx.x * blockDim.x + threadIdx.x;
  if (e >= E + N) return;
  int s, d;
  if (e < E) { s = src[e]; d = dst[e]; }
  else       { s = e - E; d = s; }
  int slot = atomicAdd(&cursor[d], 1);
  adj[slot] = s;
}

// ---------------- GraphConv ----------------
__global__ void agg_kernel(const float* __restrict__ x, const int* __restrict__ src,
                           const int* __restrict__ dst, int E, float* __restrict__ agg) {
  int e = blockIdx.x * blockDim.x + threadIdx.x;
  if (e >= E) return;
  int s = src[e], d = dst[e];
  atomicAdd(&agg[d * 2 + 0], x[s * 2 + 0]);
  atomicAdd(&agg[d * 2 + 1], x[s * 2 + 1]);
}

__global__ void graphconv_kernel(const float* __restrict__ x, const float* __restrict__ agg,
                                 const float* __restrict__ W_rel, const float* __restrict__ b_rel,
                                 const float* __restrict__ W_root,
                                 unsigned short* __restrict__ h0b, int Nn) {
  int i = blockIdx.x * blockDim.x + threadIdx.x;
  if (i >= Nn * 64) return;
  int n = i >> 6, c = i & 63;
  float a0 = agg[n * 2], a1 = agg[n * 2 + 1];
  float x0 = x[n * 2], x1 = x[n * 2 + 1];
  float v = a0 * W_rel[c] + a1 * W_rel[64 + c]
          + x0 * W_root[c] + x1 * W_root[64 + c] + b_rel[c];
  h0b[i] = f2bf(fmaxf(v, 0.f));
}

// ---------------- weight transpose+convert: W[K][N] -> Wt[N][K] bf16 -------
__global__ void wt_kernel(const float* __restrict__ W, unsigned short* __restrict__ Wt,
                          int K, int N) {
  int i = blockIdx.x * blockDim.x + threadIdx.x;
  if (i >= K * N) return;
  int n = i / K, k = i - n * K;
  Wt[i] = f2bf(W[k * N + n]);
}

// ---------------- bf16 MFMA GEMM: C[M,N] = A[M,K] @ Bt[N,K]^T --------------
// 4 waves; each wave computes a 64x64 output tile via 4x4 frags of 16x16x32.
// LDS rows: 32 bf16 (64B) padded to 80B so 16-lane row-reads spread banks.
template <int BM, int BN, int WARPS_M, int WARPS_N>
__global__ __launch_bounds__(256) void mfma_gemm(const unsigned short* __restrict__ A,
    const unsigned short* __restrict__ Bt, float* __restrict__ C, int M, int N, int K) {
  __shared__ unsigned char lds[(BM + BN) * 80];
  unsigned char* As = lds;
  unsigned char* Bs = lds + BM * 80;
  int t = threadIdx.x;
  int w = t >> 6, l = t & 63;
  int wm = w / WARPS_N, wn = w % WARPS_N;
  int row0 = blockIdx.y * BM;
  int col0 = blockIdx.x * BN;
  f32x4 acc[4][4] = {};
  int slot = l >> 4, rr = l & 15;
  for (int k0 = 0; k0 < K; k0 += 32) {
    if (k0) __syncthreads();
    // stage A tile [BM][32]
#pragma unroll
    for (int u = 0; u < BM * 4 / 256; ++u) {
      int s = t + u * 256;
      int r = s >> 2, sl = s & 3;
      int gr = row0 + r;
      uint4 v = make_uint4(0u, 0u, 0u, 0u);
      if (gr < M) v = *reinterpret_cast<const uint4*>(A + (size_t)gr * K + k0 + sl * 8);
      *reinterpret_cast<uint4*>(As + r * 80 + sl * 16) = v;
    }
    // stage B tile [BN][32] (rows of Bt = output columns)
#pragma unroll
    for (int u = 0; u < BN * 4 / 256; ++u) {
      int s = t + u * 256;
      int r = s >> 2, sl = s & 3;
      uint4 v = *reinterpret_cast<const uint4*>(Bt + (size_t)(col0 + r) * K + k0 + sl * 8);
      *reinterpret_cast<uint4*>(Bs + r * 80 + sl * 16) = v;
    }
    __syncthreads();
    bf16x8 a[4], b[4];
#pragma unroll
    for (int i = 0; i < 4; ++i)
      a[i] = *reinterpret_cast<const bf16x8*>(As + (wm * 64 + i * 16 + rr) * 80 + slot * 16);
#pragma unroll
    for (int j = 0; j < 4; ++j)
      b[j] = *reinterpret_cast<const bf16x8*>(Bs + (wn * 64 + j * 16 + rr) * 80 + slot * 16);
#pragma unroll
    for (int i = 0; i < 4; ++i)
#pragma unroll
      for (int j = 0; j < 4; ++j)
        acc[i][j] = __builtin_amdgcn_mfma_f32_16x16x32_bf16(a[i], b[j], acc[i][j], 0, 0, 0);
  }
  // C/D layout: col = l&15, row = (l>>4)*4 + reg
  int rb = row0 + wm * 64 + (l >> 4) * 4;
  int cb = col0 + wn * 64 + (l & 15);
#pragma unroll
  for (int i = 0; i < 4; ++i) {
#pragma unroll
    for (int r = 0; r < 4; ++r) {
      int gr = rb + i * 16 + r;
      if (gr < M) {
#pragma unroll
        for (int j = 0; j < 4; ++j)
          C[(size_t)gr * N + cb + j * 16] = acc[i][j][r];
      }
    }
  }
}

// ---------------- per-node attention logits al_s/al_d ----------------
template <int HC>
__global__ __launch_bounds__(HC) void al_kernel(const float* __restrict__ hW,
    const float* __restrict__ a_s, const float* __restrict__ a_d,
    float* __restrict__ alS, float* __restrict__ alD) {
  constexpr int H = HC / 64;
  int node = blockIdx.x, t = threadIdx.x;
  float v = hW[(size_t)node * HC + t];
  float ps = v * a_s[t];
  float pd = v * a_d[t];
#pragma unroll
  for (int off = 32; off; off >>= 1) {
    ps += __shfl_down(ps, off);
    pd += __shfl_down(pd, off);
  }
  if ((t & 63) == 0) {
    alS[node * H + (t >> 6)] = ps;
    alD[node * H + (t >> 6)] = pd;
  }
}

// ---------------- GAT gather, 256 channels (4 heads), bf16 output ----------
template <bool RELU>
__global__ __launch_bounds__(256) void gat_gather256(const float* __restrict__ hW,
    const float* __restrict__ alS, const float* __restrict__ alD,
    const int* __restrict__ rowptr, const int* __restrict__ adj,
    const float* __restrict__ bias, unsigned short* __restrict__ outb) {
  __shared__ float sAcc[4][256];
  __shared__ float sM[4][4];
  __shared__ float sDen[4][4];
  int node = blockIdx.x;
  int t = threadIdx.x;
  int w = t >> 6, l = t & 63;
  int head = l >> 4;
  int c = l << 2;
  float ald = alD[node * 4 + head];
  int s0 = rowptr[node], s1 = rowptr[node + 1];
  float m = -3.0e38f, den = 0.f;
  float ax = 0.f, ay = 0.f, az = 0.f, aw = 0.f;
  for (int s = s0 + w; s < s1; s += 4) {
    int src = adj[s];
    float v = alS[src * 4 + head] + ald;
    v = v > 0.f ? v : 0.2f * v;                  // leaky_relu(0.2)
    float mn = fmaxf(m, v);
    float sc = __expf(m - mn);
    float wt = __expf(v - mn);
    m = mn;
    const float4 hv = *reinterpret_cast<const float4*>(hW + (size_t)src * 256 + c);
    den = den * sc + wt;
    ax = ax * sc + wt * hv.x;
    ay = ay * sc + wt * hv.y;
    az = az * sc + wt * hv.z;
    aw = aw * sc + wt * hv.w;
  }
  if ((l & 15) == 0) { sM[w][head] = m; sDen[w][head] = den; }
  *reinterpret_cast<float4*>(&sAcc[w][c]) = make_float4(ax, ay, az, aw);
  __syncthreads();
  if (w == 0) {
    float M = fmaxf(fmaxf(sM[0][head], sM[1][head]), fmaxf(sM[2][head], sM[3][head]));
    float dtot = 0.f, bx = 0.f, by = 0.f, bz = 0.f, bw = 0.f;
#pragma unroll
    for (int ww = 0; ww < 4; ++ww) {
      float sc = __expf(sM[ww][head] - M);
      dtot += sDen[ww][head] * sc;
      const float4 av = *reinterpret_cast<const float4*>(&sAcc[ww][c]);
      bx += av.x * sc; by += av.y * sc; bz += av.z * sc; bw += av.w * sc;
    }
    float inv = 1.f / (dtot + 1e-16f);
    float o0 = bx * inv + bias[c + 0];
    float o1 = by * inv + bias[c + 1];
    float o2 = bz * inv + bias[c + 2];
    float o3 = bw * inv + bias[c + 3];
    if (RELU) {
      o0 = fmaxf(o0, 0.f); o1 = fmaxf(o1, 0.f);
      o2 = fmaxf(o2, 0.f); o3 = fmaxf(o3, 0.f);
    }
    ushort4 ov;
    ov.x = f2bf(o0); ov.y = f2bf(o1); ov.z = f2bf(o2); ov.w = f2bf(o3);
    *reinterpret_cast<ushort4*>(outb + (size_t)node * 256 + c) = ov;
  }
}

// ---------------- GAT gather, 64 channels (1 head), fp32 output ------------
template <bool RELU>
__global__ __launch_bounds__(256) void gat_gather64(const float* __restrict__ hW,
    const float* __restrict__ alS, const float* __restrict__ alD,
    const int* __restrict__ rowptr, const int* __restrict__ adj,
    const float* __restrict__ bias, float* __restrict__ out, int N) {
  int w = threadIdx.x >> 6, l = threadIdx.x & 63;
  int node = blockIdx.x * 4 + w;
  if (node >= N) return;
  int g = l >> 4;
  int c = (l & 15) << 2;
  float ald = alD[node];
  int s0 = rowptr[node], s1 = rowptr[node + 1];
  float m = -3.0e38f, den = 0.f;
  float ax = 0.f, ay = 0.f, az = 0.f, aw = 0.f;
  for (int s = s0 + g; s < s1; s += 4) {
    int src = adj[s];
    float v = alS[src] + ald;
    v = v > 0.f ? v : 0.2f * v;
    float mn = fmaxf(m, v);
    float sc = __expf(m - mn);
    float wt = __expf(v - mn);
    m = mn;
    const float4 hv = *reinterpret_cast<const float4*>(hW + (size_t)src * 64 + c);
    den = den * sc + wt;
    ax = ax * sc + wt * hv.x;
    ay = ay * sc + wt * hv.y;
    az = az * sc + wt * hv.z;
    aw = aw * sc + wt * hv.w;
  }
#pragma unroll
  for (int off = 16; off <= 32; off <<= 1) {
    float mo = __shfl_xor(m, off);
    float dn = __shfl_xor(den, off);
    float ox = __shfl_xor(ax, off), oy = __shfl_xor(ay, off);
    float oz = __shfl_xor(az, off), ow = __shfl_xor(aw, off);
    float M = fmaxf(m, mo);
    float sa = __expf(m - M), sb = __expf(mo - M);
    m = M;
    den = den * sa + dn * sb;
    ax = ax * sa + ox * sb; ay = ay * sa + oy * sb;
    az = az * sa + oz * sb; aw = aw * sa + ow * sb;
  }
  if (g == 0) {
    float inv = 1.f / (den + 1e-16f);
    float o0 = ax * inv + bias[c + 0];
    float o1 = ay * inv + bias[c + 1];
    float o2 = az * inv + bias[c + 2];
    float o3 = aw * inv + bias[c + 3];
    if (RELU) {
      o0 = fmaxf(o0, 0.f); o1 = fmaxf(o1, 0.f);
      o2 = fmaxf(o2, 0.f); o3 = fmaxf(o3, 0.f);
    }
    *reinterpret_cast<float4*>(out + (size_t)node * 64 + c) = make_float4(o0, o1, o2, o3);
  }
}

// ---------------------------------------------------------------------------
extern "C" void kernel_launch(void* const* d_in, const int* in_sizes, int n_in,
                              void* d_out, int out_size, void* d_ws, size_t ws_size,
                              hipStream_t stream) {
  const float* x      = (const float*)d_in[0];
  const float* W_rel  = (const float*)d_in[1];
  const float* b_rel  = (const float*)d_in[2];
  const float* W_root = (const float*)d_in[3];
  const float* W1     = (const float*)d_in[4];
  const float* a_s1   = (const float*)d_in[5];
  const float* a_d1   = (const float*)d_in[6];
  const float* b1     = (const float*)d_in[7];
  const float* W2     = (const float*)d_in[8];
  const float* a_s2   = (const float*)d_in[9];
  const float* a_d2   = (const float*)d_in[10];
  const float* b2     = (const float*)d_in[11];
  const float* W3     = (const float*)d_in[12];
  const float* a_s3   = (const float*)d_in[13];
  const float* a_d3   = (const float*)d_in[14];
  const float* b3     = (const float*)d_in[15];
  const int*   ei     = (const int*)d_in[16];

  int N = in_sizes[0] / 2;
  int E = in_sizes[16] / 2;
  const int* srcp = ei;
  const int* dstp = ei + E;

  // workspace layout (~90 MB). bf16 sections first (16B-aligned sizes).
  unsigned short* h0b  = (unsigned short*)d_ws;            // N*64 bf16
  unsigned short* hinb = h0b + (size_t)N * 64;             // N*256 bf16
  unsigned short* Wt1  = hinb + (size_t)N * 256;           // 256*64
  unsigned short* Wt2  = Wt1 + 256 * 64;                   // 256*256
  unsigned short* Wt3  = Wt2 + 256 * 256;                  // 64*256
  float* agg  = (float*)(Wt3 + 64 * 256);                  // N*2
  float* bufA = agg + (size_t)N * 2;                       // N*256 (GEMM out)
  float* alS  = bufA + (size_t)N * 256;                    // N*4
  float* alD  = alS + (size_t)N * 4;                       // N*4
  int* adj    = (int*)(alD + (size_t)N * 4);               // E+N
  int* rowptr = adj + (E + N);                             // N+1
  int* counts = rowptr + (N + 1);                          // N
  int* cursor = counts + N;                                // N

  hipMemsetAsync(agg, 0, (size_t)N * 2 * sizeof(float), stream);
  hipMemsetAsync(counts, 0, (size_t)N * sizeof(int), stream);

  int ESL = E + N;
  int tb = 256;

  // CSR build (shared by all 3 GAT layers)
  count_kernel<<<(ESL + tb - 1) / tb, tb, 0, stream>>>(dstp, E, N, counts);
  scan_kernel<<<1, 1024, 0, stream>>>(counts, rowptr, cursor, N);
  scatter_kernel<<<(ESL + tb - 1) / tb, tb, 0, stream>>>(srcp, dstp, E, N, cursor, adj);

  // weight transpose/convert (tiny)
  wt_kernel<<<(64 * 256 + tb - 1) / tb, tb, 0, stream>>>(W1, Wt1, 64, 256);
  wt_kernel<<<(256 * 256 + tb - 1) / tb, tb, 0, stream>>>(W2, Wt2, 256, 256);
  wt_kernel<<<(256 * 64 + tb - 1) / tb, tb, 0, stream>>>(W3, Wt3, 256, 64);

  // GraphConv (real edges only) + ReLU -> bf16
  agg_kernel<<<(E + tb - 1) / tb, tb, 0, stream>>>(x, srcp, dstp, E, agg);
  graphconv_kernel<<<(N * 64 + tb - 1) / tb, tb, 0, stream>>>(x, agg, W_rel, b_rel, W_root, h0b, N);

  dim3 gA(256 / 128, (N + 127) / 128);   // layers 1,2: N=256 -> 2 col tiles
  dim3 gB(1, (N + 255) / 256);           // layer 3: N=64

  // GAT layer 1: 64 -> 4x64, relu
  mfma_gemm<128, 128, 2, 2><<<gA, 256, 0, stream>>>(h0b, Wt1, bufA, N, 256, 64);
  al_kernel<256><<<N, 256, 0, stream>>>(bufA, a_s1, a_d1, alS, alD);
  gat_gather256<true><<<N, 256, 0, stream>>>(bufA, alS, alD, rowptr, adj, b1, hinb);

  // GAT layer 2: 256 -> 4x64, relu
  mfma_gemm<128, 128, 2, 2><<<gA, 256, 0, stream>>>(hinb, Wt2, bufA, N, 256, 256);
  al_kernel<256><<<N, 256, 0, stream>>>(bufA, a_s2, a_d2, alS, alD);
  gat_gather256<true><<<N, 256, 0, stream>>>(bufA, alS, alD, rowptr, adj, b2, hinb);

  // GAT layer 3: 256 -> 64, heads=1, no relu
  mfma_gemm<256, 64, 4, 1><<<gB, 256, 0, stream>>>(hinb, Wt3, bufA, N, 64, 256);
  al_kernel<64><<<N, 64, 0, stream>>>(bufA, a_s3, a_d3, alS, alD);
  gat_gather64<false><<<(N + 3) / 4, 256, 0, stream>>>(bufA, alS, alD, rowptr, adj, b3, (float*)d_out, N);
}

// Round 4
// 632.136 us; speedup vs baseline: 1.6342x; 1.1002x over previous
//
#include <hip/hip_runtime.h>
#include <hip/hip_bf16.h>
#include <cstdint>

// ---------------------------------------------------------------------------
// DynamicGAT: GraphConv(2->64) + GAT(64->4x64) + GAT(256->4x64) + GAT(256->64)
// R3: all inter-layer activations bf16; gathers read bf16 rows (512B/row),
// accumulate fp32, and use max-free softmax (exact algebraic identity,
// logits bounded) -> wave-per-node, zero merge, no LDS in gathers.
// ---------------------------------------------------------------------------

typedef __attribute__((ext_vector_type(8))) short bf16x8;
typedef __attribute__((ext_vector_type(4))) float f32x4;

__device__ inline unsigned short f2bf(float f) {
  union { float f; uint32_t u; } x; x.f = f;
  uint32_t r = x.u + 0x7FFF + ((x.u >> 16) & 1);   // RNE
  return (unsigned short)(r >> 16);
}
__device__ inline float bf2f(unsigned short u) {
  union { uint32_t u; float f; } x; x.u = ((uint32_t)u) << 16; return x.f;
}

// ---------------- CSR build ----------------
__global__ void count_kernel(const int* __restrict__ dst, int E, int N,
                             int* __restrict__ counts) {
  int e = blockIdx.x * blockDim.x + threadIdx.x;
  if (e >= E + N) return;
  int d = (e < E) ? dst[e] : (e - E);   // self loops appended
  atomicAdd(&counts[d], 1);
}

__global__ void scan_kernel(const int* __restrict__ counts, int* __restrict__ rowptr,
                            int* __restrict__ cursor, int n) {
  __shared__ int lds[1024];
  __shared__ int carry;
  int t = threadIdx.x;
  if (t == 0) { carry = 0; rowptr[0] = 0; }
  __syncthreads();
  for (int base = 0; base < n; base += 1024) {
    int i = base + t;
    int v = (i < n) ? counts[i] : 0;
    lds[t] = v;
    __syncthreads();
    for (int off = 1; off < 1024; off <<= 1) {
      int x = lds[t];
      if (t >= off) x += lds[t - off];
      __syncthreads();
      lds[t] = x;
      __syncthreads();
    }
    int incl = lds[t];
    int tot = lds[1023];
    int c = carry;
    if (i < n) {
      rowptr[i + 1] = c + incl;
      cursor[i] = c + incl - v;
    }
    __syncthreads();
    if (t == 0) carry = c + tot;
    __syncthreads();
  }
}

__global__ void scatter_kernel(const int* __restrict__ src, const int* __restrict__ dst,
                               int E, int N, int* __restrict__ cursor,
                               int* __restrict__ adj) {
  int e = blockIdx.x * blockDim.x + threadIdx.x;
  if (e >= E + N) return;
  int s, d;
  if (e < E) { s = src[e]; d = dst[e]; }
  else       { s = e - E; d = s; }
  int slot = atomicAdd(&cursor[d], 1);
  adj[slot] = s;
}

// ---------------- GraphConv ----------------
__global__ void agg_kernel(const float* __restrict__ x, const int* __restrict__ src,
                           const int* __restrict__ dst, int E, float* __restrict__ agg) {
  int e = blockIdx.x * blockDim.x + threadIdx.x;
  if (e >= E) return;
  int s = src[e], d = dst[e];
  atomicAdd(&agg[d * 2 + 0], x[s * 2 + 0]);
  atomicAdd(&agg[d * 2 + 1], x[s * 2 + 1]);
}

__global__ void graphconv_kernel(const float* __restrict__ x, const float* __restrict__ agg,
                                 const float* __restrict__ W_rel, const float* __restrict__ b_rel,
                                 const float* __restrict__ W_root,
                                 unsigned short* __restrict__ h0b, int Nn) {
  int i = blockIdx.x * blockDim.x + threadIdx.x;
  if (i >= Nn * 64) return;
  int n = i >> 6, c = i & 63;
  float a0 = agg[n * 2], a1 = agg[n * 2 + 1];
  float x0 = x[n * 2], x1 = x[n * 2 + 1];
  float v = a0 * W_rel[c] + a1 * W_rel[64 + c]
          + x0 * W_root[c] + x1 * W_root[64 + c] + b_rel[c];
  h0b[i] = f2bf(fmaxf(v, 0.f));
}

// ---------------- weight transpose+convert: W[K][N] -> Wt[N][K] bf16 -------
__global__ void wt_kernel(const float* __restrict__ W, unsigned short* __restrict__ Wt,
                          int K, int N) {
  int i = blockIdx.x * blockDim.x + threadIdx.x;
  if (i >= K * N) return;
  int n = i / K, k = i - n * K;
  Wt[i] = f2bf(W[k * N + n]);
}

// ---------------- bf16 MFMA GEMM: C[M,N] = A[M,K] @ Bt[N,K]^T, bf16 out ----
template <int BM, int BN, int WARPS_M, int WARPS_N>
__global__ __launch_bounds__(256) void mfma_gemm(const unsigned short* __restrict__ A,
    const unsigned short* __restrict__ Bt, unsigned short* __restrict__ C,
    int M, int N, int K) {
  __shared__ unsigned char lds[(BM + BN) * 80];
  unsigned char* As = lds;
  unsigned char* Bs = lds + BM * 80;
  int t = threadIdx.x;
  int w = t >> 6, l = t & 63;
  int wm = w / WARPS_N, wn = w % WARPS_N;
  int row0 = blockIdx.y * BM;
  int col0 = blockIdx.x * BN;
  f32x4 acc[4][4] = {};
  int slot = l >> 4, rr = l & 15;
  for (int k0 = 0; k0 < K; k0 += 32) {
    if (k0) __syncthreads();
#pragma unroll
    for (int u = 0; u < BM * 4 / 256; ++u) {
      int s = t + u * 256;
      int r = s >> 2, sl = s & 3;
      int gr = row0 + r;
      uint4 v = make_uint4(0u, 0u, 0u, 0u);
      if (gr < M) v = *reinterpret_cast<const uint4*>(A + (size_t)gr * K + k0 + sl * 8);
      *reinterpret_cast<uint4*>(As + r * 80 + sl * 16) = v;
    }
#pragma unroll
    for (int u = 0; u < BN * 4 / 256; ++u) {
      int s = t + u * 256;
      int r = s >> 2, sl = s & 3;
      uint4 v = *reinterpret_cast<const uint4*>(Bt + (size_t)(col0 + r) * K + k0 + sl * 8);
      *reinterpret_cast<uint4*>(Bs + r * 80 + sl * 16) = v;
    }
    __syncthreads();
    bf16x8 a[4], b[4];
#pragma unroll
    for (int i = 0; i < 4; ++i)
      a[i] = *reinterpret_cast<const bf16x8*>(As + (wm * 64 + i * 16 + rr) * 80 + slot * 16);
#pragma unroll
    for (int j = 0; j < 4; ++j)
      b[j] = *reinterpret_cast<const bf16x8*>(Bs + (wn * 64 + j * 16 + rr) * 80 + slot * 16);
#pragma unroll
    for (int i = 0; i < 4; ++i)
#pragma unroll
      for (int j = 0; j < 4; ++j)
        acc[i][j] = __builtin_amdgcn_mfma_f32_16x16x32_bf16(a[i], b[j], acc[i][j], 0, 0, 0);
  }
  int rb = row0 + wm * 64 + (l >> 4) * 4;
  int cb = col0 + wn * 64 + (l & 15);
#pragma unroll
  for (int i = 0; i < 4; ++i) {
#pragma unroll
    for (int r = 0; r < 4; ++r) {
      int gr = rb + i * 16 + r;
      if (gr < M) {
#pragma unroll
        for (int j = 0; j < 4; ++j)
          C[(size_t)gr * N + cb + j * 16] = f2bf(acc[i][j][r]);
      }
    }
  }
}

// ---------------- per-node attention logits (bf16 input) ----------------
template <int HC>
__global__ __launch_bounds__(HC) void al_kernel(const unsigned short* __restrict__ hW,
    const float* __restrict__ a_s, const float* __restrict__ a_d,
    float* __restrict__ alS, float* __restrict__ alD) {
  constexpr int H = HC / 64;
  int node = blockIdx.x, t = threadIdx.x;
  float v = bf2f(hW[(size_t)node * HC + t]);
  float ps = v * a_s[t];
  float pd = v * a_d[t];
#pragma unroll
  for (int off = 32; off; off >>= 1) {
    ps += __shfl_down(ps, off);
    pd += __shfl_down(pd, off);
  }
  if ((t & 63) == 0) {
    alS[node * H + (t >> 6)] = ps;
    alD[node * H + (t >> 6)] = pd;
  }
}

// ---------------- GAT gather, 256 ch (4 heads), bf16 in/out ----------------
// wave per node (4 nodes/block). Lane l covers channels [4l,4l+4), head=l>>4.
// Max-free softmax: den/acc are plain sums (logits bounded, exp safe).
template <bool RELU>
__global__ __launch_bounds__(256) void gat_gather256(const unsigned short* __restrict__ hW,
    const float* __restrict__ alS, const float* __restrict__ alD,
    const int* __restrict__ rowptr, const int* __restrict__ adj,
    const float* __restrict__ bias, unsigned short* __restrict__ outb, int N) {
  int w = threadIdx.x >> 6, l = threadIdx.x & 63;
  int node = blockIdx.x * 4 + w;
  if (node >= N) return;
  int head = l >> 4;
  int c = l << 2;
  float ald = alD[node * 4 + head];
  int s0 = rowptr[node], s1 = rowptr[node + 1];
  float den = 0.f, a0 = 0.f, a1 = 0.f, a2 = 0.f, a3 = 0.f;
  for (int s = s0; s < s1; ++s) {
    int src = adj[s];
    float v = alS[src * 4 + head] + ald;
    v = v > 0.f ? v : 0.2f * v;                  // leaky_relu(0.2)
    float wt = __expf(v);
    ushort4 hv = *reinterpret_cast<const ushort4*>(hW + (size_t)src * 256 + c);
    den += wt;
    a0 += wt * bf2f(hv.x);
    a1 += wt * bf2f(hv.y);
    a2 += wt * bf2f(hv.z);
    a3 += wt * bf2f(hv.w);
  }
  float inv = 1.f / (den + 1e-16f);
  float o0 = a0 * inv + bias[c + 0];
  float o1 = a1 * inv + bias[c + 1];
  float o2 = a2 * inv + bias[c + 2];
  float o3 = a3 * inv + bias[c + 3];
  if (RELU) {
    o0 = fmaxf(o0, 0.f); o1 = fmaxf(o1, 0.f);
    o2 = fmaxf(o2, 0.f); o3 = fmaxf(o3, 0.f);
  }
  ushort4 ov;
  ov.x = f2bf(o0); ov.y = f2bf(o1); ov.z = f2bf(o2); ov.w = f2bf(o3);
  *reinterpret_cast<ushort4*>(outb + (size_t)node * 256 + c) = ov;
}

// ---------------- GAT gather, 64 ch (1 head), bf16 in, fp32 out ------------
// wave per node (4 nodes/block); 4 groups of 16 lanes stride edges; lane
// covers channels [(l&15)*4, +4). Merge = pure sum via shfl_xor(16,32).
template <bool RELU>
__global__ __launch_bounds__(256) void gat_gather64(const unsigned short* __restrict__ hW,
    const float* __restrict__ alS, const float* __restrict__ alD,
    const int* __restrict__ rowptr, const int* __restrict__ adj,
    const float* __restrict__ bias, float* __restrict__ out, int N) {
  int w = threadIdx.x >> 6, l = threadIdx.x & 63;
  int node = blockIdx.x * 4 + w;
  if (node >= N) return;
  int g = l >> 4;
  int c = (l & 15) << 2;
  float ald = alD[node];
  int s0 = rowptr[node], s1 = rowptr[node + 1];
  float den = 0.f, a0 = 0.f, a1 = 0.f, a2 = 0.f, a3 = 0.f;
  for (int s = s0 + g; s < s1; s += 4) {
    int src = adj[s];
    float v = alS[src] + ald;
    v = v > 0.f ? v : 0.2f * v;
    float wt = __expf(v);
    ushort4 hv = *reinterpret_cast<const ushort4*>(hW + (size_t)src * 64 + c);
    den += wt;
    a0 += wt * bf2f(hv.x);
    a1 += wt * bf2f(hv.y);
    a2 += wt * bf2f(hv.z);
    a3 += wt * bf2f(hv.w);
  }
#pragma unroll
  for (int off = 16; off <= 32; off <<= 1) {
    den += __shfl_xor(den, off);
    a0 += __shfl_xor(a0, off);
    a1 += __shfl_xor(a1, off);
    a2 += __shfl_xor(a2, off);
    a3 += __shfl_xor(a3, off);
  }
  if (g == 0) {
    float inv = 1.f / (den + 1e-16f);
    float o0 = a0 * inv + bias[c + 0];
    float o1 = a1 * inv + bias[c + 1];
    float o2 = a2 * inv + bias[c + 2];
    float o3 = a3 * inv + bias[c + 3];
    if (RELU) {
      o0 = fmaxf(o0, 0.f); o1 = fmaxf(o1, 0.f);
      o2 = fmaxf(o2, 0.f); o3 = fmaxf(o3, 0.f);
    }
    *reinterpret_cast<float4*>(out + (size_t)node * 64 + c) = make_float4(o0, o1, o2, o3);
  }
}

// ---------------------------------------------------------------------------
extern "C" void kernel_launch(void* const* d_in, const int* in_sizes, int n_in,
                              void* d_out, int out_size, void* d_ws, size_t ws_size,
                              hipStream_t stream) {
  const float* x      = (const float*)d_in[0];
  const float* W_rel  = (const float*)d_in[1];
  const float* b_rel  = (const float*)d_in[2];
  const float* W_root = (const float*)d_in[3];
  const float* W1     = (const float*)d_in[4];
  const float* a_s1   = (const float*)d_in[5];
  const float* a_d1   = (const float*)d_in[6];
  const float* b1     = (const float*)d_in[7];
  const float* W2     = (const float*)d_in[8];
  const float* a_s2   = (const float*)d_in[9];
  const float* a_d2   = (const float*)d_in[10];
  const float* b2     = (const float*)d_in[11];
  const float* W3     = (const float*)d_in[12];
  const float* a_s3   = (const float*)d_in[13];
  const float* a_d3   = (const float*)d_in[14];
  const float* b3     = (const float*)d_in[15];
  const int*   ei     = (const int*)d_in[16];

  int N = in_sizes[0] / 2;
  int E = in_sizes[16] / 2;
  const int* srcp = ei;
  const int* dstp = ei + E;

  // workspace layout (~75 MB), bf16 sections 16B-aligned
  unsigned short* h0b  = (unsigned short*)d_ws;            // N*64 bf16
  unsigned short* bufX = h0b + (size_t)N * 64;             // N*256 bf16
  unsigned short* bufY = bufX + (size_t)N * 256;           // N*256 bf16
  unsigned short* bufZ = bufY + (size_t)N * 256;           // N*64 bf16
  unsigned short* Wt1  = bufZ + (size_t)N * 64;            // 256*64
  unsigned short* Wt2  = Wt1 + 256 * 64;                   // 256*256
  unsigned short* Wt3  = Wt2 + 256 * 256;                  // 64*256
  float* agg  = (float*)(Wt3 + 64 * 256);                  // N*2
  float* alS  = agg + (size_t)N * 2;                       // N*4
  float* alD  = alS + (size_t)N * 4;                       // N*4
  int* adj    = (int*)(alD + (size_t)N * 4);               // E+N
  int* rowptr = adj + (E + N);                             // N+1
  int* counts = rowptr + (N + 1);                          // N
  int* cursor = counts + N;                                // N

  hipMemsetAsync(agg, 0, (size_t)N * 2 * sizeof(float), stream);
  hipMemsetAsync(counts, 0, (size_t)N * sizeof(int), stream);

  int ESL = E + N;
  int tb = 256;

  // CSR build (shared by all 3 GAT layers)
  count_kernel<<<(ESL + tb - 1) / tb, tb, 0, stream>>>(dstp, E, N, counts);
  scan_kernel<<<1, 1024, 0, stream>>>(counts, rowptr, cursor, N);
  scatter_kernel<<<(ESL + tb - 1) / tb, tb, 0, stream>>>(srcp, dstp, E, N, cursor, adj);

  // weight transpose/convert (tiny)
  wt_kernel<<<(64 * 256 + tb - 1) / tb, tb, 0, stream>>>(W1, Wt1, 64, 256);
  wt_kernel<<<(256 * 256 + tb - 1) / tb, tb, 0, stream>>>(W2, Wt2, 256, 256);
  wt_kernel<<<(256 * 64 + tb - 1) / tb, tb, 0, stream>>>(W3, Wt3, 256, 64);

  // GraphConv (real edges only) + ReLU -> bf16
  agg_kernel<<<(E + tb - 1) / tb, tb, 0, stream>>>(x, srcp, dstp, E, agg);
  graphconv_kernel<<<(N * 64 + tb - 1) / tb, tb, 0, stream>>>(x, agg, W_rel, b_rel, W_root, h0b, N);

  dim3 gA(256 / 128, (N + 127) / 128);   // layers 1,2: N=256 -> 2 col tiles
  dim3 gB(1, (N + 255) / 256);           // layer 3: N=64
  int gN4 = (N + 3) / 4;

  // GAT layer 1: 64 -> 4x64, relu
  mfma_gemm<128, 128, 2, 2><<<gA, 256, 0, stream>>>(h0b, Wt1, bufX, N, 256, 64);
  al_kernel<256><<<N, 256, 0, stream>>>(bufX, a_s1, a_d1, alS, alD);
  gat_gather256<true><<<gN4, 256, 0, stream>>>(bufX, alS, alD, rowptr, adj, b1, bufY, N);

  // GAT layer 2: 256 -> 4x64, relu
  mfma_gemm<128, 128, 2, 2><<<gA, 256, 0, stream>>>(bufY, Wt2, bufX, N, 256, 256);
  al_kernel<256><<<N, 256, 0, stream>>>(bufX, a_s2, a_d2, alS, alD);
  gat_gather256<true><<<gN4, 256, 0, stream>>>(bufX, alS, alD, rowptr, adj, b2, bufY, N);

  // GAT layer 3: 256 -> 64, heads=1, no relu
  mfma_gemm<256, 64, 4, 1><<<gB, 256, 0, stream>>>(bufY, Wt3, bufZ, N, 64, 256);
  al_kernel<64><<<N, 64, 0, stream>>>(bufZ, a_s3, a_d3, alS, alD);
  gat_gather64<false><<<gN4, 256, 0, stream>>>(bufZ, alS, alD, rowptr, adj, b3, (float*)d_out, N);
}

// Round 5
// 506.531 us; speedup vs baseline: 2.0395x; 1.2480x over previous
//
#include <hip/hip_runtime.h>
#include <hip/hip_bf16.h>
#include <cstdint>

// ---------------------------------------------------------------------------
// DynamicGAT: GraphConv(2->64) + GAT(64->4x64) + GAT(256->4x64) + GAT(256->64)
// R4: gathers unrolled 4x (12 outstanding loads/wave, latency -> bandwidth
// bound); attention logits al_s/al_d fused into the MFMA GEMM epilogue
// (warp col-block == one head; 16-lane shfl butterfly, no extra pass).
// ---------------------------------------------------------------------------

typedef __attribute__((ext_vector_type(8))) short bf16x8;
typedef __attribute__((ext_vector_type(4))) float f32x4;

__device__ inline unsigned short f2bf(float f) {
  union { float f; uint32_t u; } x; x.f = f;
  uint32_t r = x.u + 0x7FFF + ((x.u >> 16) & 1);   // RNE
  return (unsigned short)(r >> 16);
}
__device__ inline float bf2f(unsigned short u) {
  union { uint32_t u; float f; } x; x.u = ((uint32_t)u) << 16; return x.f;
}
__device__ inline float lrelu02(float v) { return v > 0.f ? v : 0.2f * v; }

// ---------------- CSR build ----------------
__global__ void count_kernel(const int* __restrict__ dst, int E, int N,
                             int* __restrict__ counts) {
  int e = blockIdx.x * blockDim.x + threadIdx.x;
  if (e >= E + N) return;
  int d = (e < E) ? dst[e] : (e - E);   // self loops appended
  atomicAdd(&counts[d], 1);
}

__global__ void scan_kernel(const int* __restrict__ counts, int* __restrict__ rowptr,
                            int* __restrict__ cursor, int n) {
  __shared__ int lds[1024];
  __shared__ int carry;
  int t = threadIdx.x;
  if (t == 0) { carry = 0; rowptr[0] = 0; }
  __syncthreads();
  for (int base = 0; base < n; base += 1024) {
    int i = base + t;
    int v = (i < n) ? counts[i] : 0;
    lds[t] = v;
    __syncthreads();
    for (int off = 1; off < 1024; off <<= 1) {
      int x = lds[t];
      if (t >= off) x += lds[t - off];
      __syncthreads();
      lds[t] = x;
      __syncthreads();
    }
    int incl = lds[t];
    int tot = lds[1023];
    int c = carry;
    if (i < n) {
      rowptr[i + 1] = c + incl;
      cursor[i] = c + incl - v;
    }
    __syncthreads();
    if (t == 0) carry = c + tot;
    __syncthreads();
  }
}

__global__ void scatter_kernel(const int* __restrict__ src, const int* __restrict__ dst,
                               int E, int N, int* __restrict__ cursor,
                               int* __restrict__ adj) {
  int e = blockIdx.x * blockDim.x + threadIdx.x;
  if (e >= E + N) return;
  int s, d;
  if (e < E) { s = src[e]; d = dst[e]; }
  else       { s = e - E; d = s; }
  int slot = atomicAdd(&cursor[d], 1);
  adj[slot] = s;
}

// ---------------- GraphConv ----------------
__global__ void agg_kernel(const float* __restrict__ x, const int* __restrict__ src,
                           const int* __restrict__ dst, int E, float* __restrict__ agg) {
  int e = blockIdx.x * blockDim.x + threadIdx.x;
  if (e >= E) return;
  int s = src[e], d = dst[e];
  atomicAdd(&agg[d * 2 + 0], x[s * 2 + 0]);
  atomicAdd(&agg[d * 2 + 1], x[s * 2 + 1]);
}

__global__ void graphconv_kernel(const float* __restrict__ x, const float* __restrict__ agg,
                                 const float* __restrict__ W_rel, const float* __restrict__ b_rel,
                                 const float* __restrict__ W_root,
                                 unsigned short* __restrict__ h0b, int Nn) {
  int i = blockIdx.x * blockDim.x + threadIdx.x;
  if (i >= Nn * 64) return;
  int n = i >> 6, c = i & 63;
  float a0 = agg[n * 2], a1 = agg[n * 2 + 1];
  float x0 = x[n * 2], x1 = x[n * 2 + 1];
  float v = a0 * W_rel[c] + a1 * W_rel[64 + c]
          + x0 * W_root[c] + x1 * W_root[64 + c] + b_rel[c];
  h0b[i] = f2bf(fmaxf(v, 0.f));
}

// ---------------- weight transpose+convert: W[K][N] -> Wt[N][K] bf16 -------
__global__ void wt_kernel(const float* __restrict__ W, unsigned short* __restrict__ Wt,
                          int K, int N) {
  int i = blockIdx.x * blockDim.x + threadIdx.x;
  if (i >= K * N) return;
  int n = i / K, k = i - n * K;
  Wt[i] = f2bf(W[k * N + n]);
}

// ---------------- bf16 MFMA GEMM + fused attention logits ------------------
// C[M,N] = A[M,K] @ Bt[N,K]^T (bf16 out, fp32 accum). Each warp's 64-col
// block is exactly one head: epilogue computes al_s/al_d per row via 4-term
// dot + 16-lane shfl butterfly, stores to alS/alD[row*H + head].
template <int BM, int BN, int WARPS_M, int WARPS_N, int H>
__global__ __launch_bounds__(256) void mfma_gemm(const unsigned short* __restrict__ A,
    const unsigned short* __restrict__ Bt, unsigned short* __restrict__ C,
    const float* __restrict__ a_s, const float* __restrict__ a_d,
    float* __restrict__ alS, float* __restrict__ alD, int M, int N, int K) {
  __shared__ unsigned char lds[(BM + BN) * 80];
  unsigned char* As = lds;
  unsigned char* Bs = lds + BM * 80;
  int t = threadIdx.x;
  int w = t >> 6, l = t & 63;
  int wm = w / WARPS_N, wn = w % WARPS_N;
  int row0 = blockIdx.y * BM;
  int col0 = blockIdx.x * BN;
  f32x4 acc[4][4] = {};
  int slot = l >> 4, rr = l & 15;
  for (int k0 = 0; k0 < K; k0 += 32) {
    if (k0) __syncthreads();
#pragma unroll
    for (int u = 0; u < BM * 4 / 256; ++u) {
      int s = t + u * 256;
      int r = s >> 2, sl = s & 3;
      int gr = row0 + r;
      uint4 v = make_uint4(0u, 0u, 0u, 0u);
      if (gr < M) v = *reinterpret_cast<const uint4*>(A + (size_t)gr * K + k0 + sl * 8);
      *reinterpret_cast<uint4*>(As + r * 80 + sl * 16) = v;
    }
#pragma unroll
    for (int u = 0; u < BN * 4 / 256; ++u) {
      int s = t + u * 256;
      int r = s >> 2, sl = s & 3;
      uint4 v = *reinterpret_cast<const uint4*>(Bt + (size_t)(col0 + r) * K + k0 + sl * 8);
      *reinterpret_cast<uint4*>(Bs + r * 80 + sl * 16) = v;
    }
    __syncthreads();
    bf16x8 a[4], b[4];
#pragma unroll
    for (int i = 0; i < 4; ++i)
      a[i] = *reinterpret_cast<const bf16x8*>(As + (wm * 64 + i * 16 + rr) * 80 + slot * 16);
#pragma unroll
    for (int j = 0; j < 4; ++j)
      b[j] = *reinterpret_cast<const bf16x8*>(Bs + (wn * 64 + j * 16 + rr) * 80 + slot * 16);
#pragma unroll
    for (int i = 0; i < 4; ++i)
#pragma unroll
      for (int j = 0; j < 4; ++j)
        acc[i][j] = __builtin_amdgcn_mfma_f32_16x16x32_bf16(a[i], b[j], acc[i][j], 0, 0, 0);
  }
  // C write. C/D layout: col = l&15, row = (l>>4)*4 + reg
  int rb = row0 + wm * 64 + (l >> 4) * 4;
  int cb = col0 + wn * 64 + (l & 15);
#pragma unroll
  for (int i = 0; i < 4; ++i) {
#pragma unroll
    for (int r = 0; r < 4; ++r) {
      int gr = rb + i * 16 + r;
      if (gr < M) {
#pragma unroll
        for (int j = 0; j < 4; ++j)
          C[(size_t)gr * N + cb + j * 16] = f2bf(acc[i][j][r]);
      }
    }
  }
  // fused logits: this warp's head
  int hd = (col0 >> 6) + wn;
  int ch = l & 15;
  float as0 = a_s[hd * 64 + ch], as1 = a_s[hd * 64 + ch + 16];
  float as2 = a_s[hd * 64 + ch + 32], as3 = a_s[hd * 64 + ch + 48];
  float ad0 = a_d[hd * 64 + ch], ad1 = a_d[hd * 64 + ch + 16];
  float ad2 = a_d[hd * 64 + ch + 32], ad3 = a_d[hd * 64 + ch + 48];
#pragma unroll
  for (int i = 0; i < 4; ++i) {
#pragma unroll
    for (int r = 0; r < 4; ++r) {
      float ps = acc[i][0][r] * as0 + acc[i][1][r] * as1
               + acc[i][2][r] * as2 + acc[i][3][r] * as3;
      float pd = acc[i][0][r] * ad0 + acc[i][1][r] * ad1
               + acc[i][2][r] * ad2 + acc[i][3][r] * ad3;
#pragma unroll
      for (int off = 1; off < 16; off <<= 1) {
        ps += __shfl_xor(ps, off);
        pd += __shfl_xor(pd, off);
      }
      if ((l & 15) == 0) {
        int gr = rb + i * 16 + r;
        if (gr < M) {
          alS[gr * H + hd] = ps;
          alD[gr * H + hd] = pd;
        }
      }
    }
  }
}

// ---------------- GAT gather, 256 ch (4 heads), bf16 in/out ----------------
// wave per node; lane l covers channels [4l,4l+4), head=l>>4. Max-free
// softmax (exact: ratio invariant, logits bounded). 4x edge unroll for MLP.
template <bool RELU>
__global__ __launch_bounds__(256) void gat_gather256(const unsigned short* __restrict__ hW,
    const float* __restrict__ alS, const float* __restrict__ alD,
    const int* __restrict__ rowptr, const int* __restrict__ adj,
    const float* __restrict__ bias, unsigned short* __restrict__ outb, int N) {
  int w = threadIdx.x >> 6, l = threadIdx.x & 63;
  int node = blockIdx.x * 4 + w;
  if (node >= N) return;
  int head = l >> 4;
  int c = l << 2;
  float ald = alD[node * 4 + head];
  int s0 = rowptr[node], s1 = rowptr[node + 1];
  float den = 0.f, a0 = 0.f, a1 = 0.f, a2 = 0.f, a3 = 0.f;
  int s = s0;
  for (; s + 4 <= s1; s += 4) {
    int i0 = adj[s + 0], i1 = adj[s + 1], i2 = adj[s + 2], i3 = adj[s + 3];
    float v0 = alS[i0 * 4 + head];
    float v1 = alS[i1 * 4 + head];
    float v2 = alS[i2 * 4 + head];
    float v3 = alS[i3 * 4 + head];
    ushort4 h0 = *reinterpret_cast<const ushort4*>(hW + (size_t)i0 * 256 + c);
    ushort4 h1 = *reinterpret_cast<const ushort4*>(hW + (size_t)i1 * 256 + c);
    ushort4 h2 = *reinterpret_cast<const ushort4*>(hW + (size_t)i2 * 256 + c);
    ushort4 h3 = *reinterpret_cast<const ushort4*>(hW + (size_t)i3 * 256 + c);
    float w0 = __expf(lrelu02(v0 + ald));
    float w1 = __expf(lrelu02(v1 + ald));
    float w2 = __expf(lrelu02(v2 + ald));
    float w3 = __expf(lrelu02(v3 + ald));
    den += (w0 + w1) + (w2 + w3);
    a0 += w0 * bf2f(h0.x) + w1 * bf2f(h1.x) + w2 * bf2f(h2.x) + w3 * bf2f(h3.x);
    a1 += w0 * bf2f(h0.y) + w1 * bf2f(h1.y) + w2 * bf2f(h2.y) + w3 * bf2f(h3.y);
    a2 += w0 * bf2f(h0.z) + w1 * bf2f(h1.z) + w2 * bf2f(h2.z) + w3 * bf2f(h3.z);
    a3 += w0 * bf2f(h0.w) + w1 * bf2f(h1.w) + w2 * bf2f(h2.w) + w3 * bf2f(h3.w);
  }
  for (; s < s1; ++s) {
    int i0 = adj[s];
    float v0 = alS[i0 * 4 + head];
    ushort4 h0 = *reinterpret_cast<const ushort4*>(hW + (size_t)i0 * 256 + c);
    float w0 = __expf(lrelu02(v0 + ald));
    den += w0;
    a0 += w0 * bf2f(h0.x);
    a1 += w0 * bf2f(h0.y);
    a2 += w0 * bf2f(h0.z);
    a3 += w0 * bf2f(h0.w);
  }
  float inv = 1.f / (den + 1e-16f);
  float o0 = a0 * inv + bias[c + 0];
  float o1 = a1 * inv + bias[c + 1];
  float o2 = a2 * inv + bias[c + 2];
  float o3 = a3 * inv + bias[c + 3];
  if (RELU) {
    o0 = fmaxf(o0, 0.f); o1 = fmaxf(o1, 0.f);
    o2 = fmaxf(o2, 0.f); o3 = fmaxf(o3, 0.f);
  }
  ushort4 ov;
  ov.x = f2bf(o0); ov.y = f2bf(o1); ov.z = f2bf(o2); ov.w = f2bf(o3);
  *reinterpret_cast<ushort4*>(outb + (size_t)node * 256 + c) = ov;
}

// ---------------- GAT gather, 64 ch (1 head), bf16 in, fp32 out ------------
// wave per node; 4 groups of 16 lanes stride edges (2x unrolled); lane covers
// channels [(l&15)*4, +4). Merge = pure sum via shfl_xor(16,32).
template <bool RELU>
__global__ __launch_bounds__(256) void gat_gather64(const unsigned short* __restrict__ hW,
    const float* __restrict__ alS, const float* __restrict__ alD,
    const int* __restrict__ rowptr, const int* __restrict__ adj,
    const float* __restrict__ bias, float* __restrict__ out, int N) {
  int w = threadIdx.x >> 6, l = threadIdx.x & 63;
  int node = blockIdx.x * 4 + w;
  if (node >= N) return;
  int g = l >> 4;
  int c = (l & 15) << 2;
  float ald = alD[node];
  int s0 = rowptr[node], s1 = rowptr[node + 1];
  float den = 0.f, a0 = 0.f, a1 = 0.f, a2 = 0.f, a3 = 0.f;
  int s = s0 + g;
  for (; s + 4 < s1; s += 8) {
    int i0 = adj[s], i1 = adj[s + 4];
    float v0 = alS[i0], v1 = alS[i1];
    ushort4 h0 = *reinterpret_cast<const ushort4*>(hW + (size_t)i0 * 64 + c);
    ushort4 h1 = *reinterpret_cast<const ushort4*>(hW + (size_t)i1 * 64 + c);
    float w0 = __expf(lrelu02(v0 + ald));
    float w1 = __expf(lrelu02(v1 + ald));
    den += w0 + w1;
    a0 += w0 * bf2f(h0.x) + w1 * bf2f(h1.x);
    a1 += w0 * bf2f(h0.y) + w1 * bf2f(h1.y);
    a2 += w0 * bf2f(h0.z) + w1 * bf2f(h1.z);
    a3 += w0 * bf2f(h0.w) + w1 * bf2f(h1.w);
  }
  if (s < s1) {
    int i0 = adj[s];
    float v0 = alS[i0];
    ushort4 h0 = *reinterpret_cast<const ushort4*>(hW + (size_t)i0 * 64 + c);
    float w0 = __expf(lrelu02(v0 + ald));
    den += w0;
    a0 += w0 * bf2f(h0.x);
    a1 += w0 * bf2f(h0.y);
    a2 += w0 * bf2f(h0.z);
    a3 += w0 * bf2f(h0.w);
  }
#pragma unroll
  for (int off = 16; off <= 32; off <<= 1) {
    den += __shfl_xor(den, off);
    a0 += __shfl_xor(a0, off);
    a1 += __shfl_xor(a1, off);
    a2 += __shfl_xor(a2, off);
    a3 += __shfl_xor(a3, off);
  }
  if (g == 0) {
    float inv = 1.f / (den + 1e-16f);
    float o0 = a0 * inv + bias[c + 0];
    float o1 = a1 * inv + bias[c + 1];
    float o2 = a2 * inv + bias[c + 2];
    float o3 = a3 * inv + bias[c + 3];
    if (RELU) {
      o0 = fmaxf(o0, 0.f); o1 = fmaxf(o1, 0.f);
      o2 = fmaxf(o2, 0.f); o3 = fmaxf(o3, 0.f);
    }
    *reinterpret_cast<float4*>(out + (size_t)node * 64 + c) = make_float4(o0, o1, o2, o3);
  }
}

// ---------------------------------------------------------------------------
extern "C" void kernel_launch(void* const* d_in, const int* in_sizes, int n_in,
                              void* d_out, int out_size, void* d_ws, size_t ws_size,
                              hipStream_t stream) {
  const float* x      = (const float*)d_in[0];
  const float* W_rel  = (const float*)d_in[1];
  const float* b_rel  = (const float*)d_in[2];
  const float* W_root = (const float*)d_in[3];
  const float* W1     = (const float*)d_in[4];
  const float* a_s1   = (const float*)d_in[5];
  const float* a_d1   = (const float*)d_in[6];
  const float* b1     = (const float*)d_in[7];
  const float* W2     = (const float*)d_in[8];
  const float* a_s2   = (const float*)d_in[9];
  const float* a_d2   = (const float*)d_in[10];
  const float* b2     = (const float*)d_in[11];
  const float* W3     = (const float*)d_in[12];
  const float* a_s3   = (const float*)d_in[13];
  const float* a_d3   = (const float*)d_in[14];
  const float* b3     = (const float*)d_in[15];
  const int*   ei     = (const int*)d_in[16];

  int N = in_sizes[0] / 2;
  int E = in_sizes[16] / 2;
  const int* srcp = ei;
  const int* dstp = ei + E;

  // workspace layout (~75 MB), bf16 sections 16B-aligned
  unsigned short* h0b  = (unsigned short*)d_ws;            // N*64 bf16
  unsigned short* bufX = h0b + (size_t)N * 64;             // N*256 bf16
  unsigned short* bufY = bufX + (size_t)N * 256;           // N*256 bf16
  unsigned short* bufZ = bufY + (size_t)N * 256;           // N*64 bf16
  unsigned short* Wt1  = bufZ + (size_t)N * 64;            // 256*64
  unsigned short* Wt2  = Wt1 + 256 * 64;                   // 256*256
  unsigned short* Wt3  = Wt2 + 256 * 256;                  // 64*256
  float* agg  = (float*)(Wt3 + 64 * 256);                  // N*2
  float* alS  = agg + (size_t)N * 2;                       // N*4
  float* alD  = alS + (size_t)N * 4;                       // N*4
  int* adj    = (int*)(alD + (size_t)N * 4);               // E+N
  int* rowptr = adj + (E + N);                             // N+1
  int* counts = rowptr + (N + 1);                          // N
  int* cursor = counts + N;                                // N

  hipMemsetAsync(agg, 0, (size_t)N * 2 * sizeof(float), stream);
  hipMemsetAsync(counts, 0, (size_t)N * sizeof(int), stream);

  int ESL = E + N;
  int tb = 256;

  // CSR build (shared by all 3 GAT layers)
  count_kernel<<<(ESL + tb - 1) / tb, tb, 0, stream>>>(dstp, E, N, counts);
  scan_kernel<<<1, 1024, 0, stream>>>(counts, rowptr, cursor, N);
  scatter_kernel<<<(ESL + tb - 1) / tb, tb, 0, stream>>>(srcp, dstp, E, N, cursor, adj);

  // weight transpose/convert (tiny)
  wt_kernel<<<(64 * 256 + tb - 1) / tb, tb, 0, stream>>>(W1, Wt1, 64, 256);
  wt_kernel<<<(256 * 256 + tb - 1) / tb, tb, 0, stream>>>(W2, Wt2, 256, 256);
  wt_kernel<<<(256 * 64 + tb - 1) / tb, tb, 0, stream>>>(W3, Wt3, 256, 64);

  // GraphConv (real edges only) + ReLU -> bf16
  agg_kernel<<<(E + tb - 1) / tb, tb, 0, stream>>>(x, srcp, dstp, E, agg);
  graphconv_kernel<<<(N * 64 + tb - 1) / tb, tb, 0, stream>>>(x, agg, W_rel, b_rel, W_root, h0b, N);

  dim3 gA(256 / 128, (N + 127) / 128);   // layers 1,2: N=256 -> 2 col tiles
  dim3 gB(1, (N + 255) / 256);           // layer 3: N=64
  int gN4 = (N + 3) / 4;

  // GAT layer 1: 64 -> 4x64, relu
  mfma_gemm<128, 128, 2, 2, 4><<<gA, 256, 0, stream>>>(h0b, Wt1, bufX, a_s1, a_d1, alS, alD, N, 256, 64);
  gat_gather256<true><<<gN4, 256, 0, stream>>>(bufX, alS, alD, rowptr, adj, b1, bufY, N);

  // GAT layer 2: 256 -> 4x64, relu
  mfma_gemm<128, 128, 2, 2, 4><<<gA, 256, 0, stream>>>(bufY, Wt2, bufX, a_s2, a_d2, alS, alD, N, 256, 256);
  gat_gather256<true><<<gN4, 256, 0, stream>>>(bufX, alS, alD, rowptr, adj, b2, bufY, N);

  // GAT layer 3: 256 -> 64, heads=1, no relu
  mfma_gemm<256, 64, 4, 1, 1><<<gB, 256, 0, stream>>>(bufY, Wt3, bufZ, a_s3, a_d3, alS, alD, N, 64, 256);
  gat_gather64<false><<<gN4, 256, 0, stream>>>(bufZ, alS, alD, rowptr, adj, b3, (float*)d_out, N);
}

// Round 6
// 429.798 us; speedup vs baseline: 2.4036x; 1.1785x over previous
//
#include <hip/hip_runtime.h>
#include <hip/hip_bf16.h>
#include <cstdint>

// ---------------------------------------------------------------------------
// DynamicGAT: GraphConv(2->64) + GAT(64->4x64) + GAT(256->4x64) + GAT(256->64)
// R5: single-block scan (93us, 0.17% occupancy) replaced by 3-pass
// device-wide scan (~8us). Rest unchanged from R4.
// ---------------------------------------------------------------------------

typedef __attribute__((ext_vector_type(8))) short bf16x8;
typedef __attribute__((ext_vector_type(4))) float f32x4;

__device__ inline unsigned short f2bf(float f) {
  union { float f; uint32_t u; } x; x.f = f;
  uint32_t r = x.u + 0x7FFF + ((x.u >> 16) & 1);   // RNE
  return (unsigned short)(r >> 16);
}
__device__ inline float bf2f(unsigned short u) {
  union { uint32_t u; float f; } x; x.u = ((uint32_t)u) << 16; return x.f;
}
__device__ inline float lrelu02(float v) { return v > 0.f ? v : 0.2f * v; }

// ---------------- CSR build ----------------
__global__ void count_kernel(const int* __restrict__ dst, int E, int N,
                             int* __restrict__ counts) {
  int e = blockIdx.x * blockDim.x + threadIdx.x;
  if (e >= E + N) return;
  int d = (e < E) ? dst[e] : (e - E);   // self loops appended
  atomicAdd(&counts[d], 1);
}

// 3-pass device-wide exclusive scan of counts[0..n) -> rowptr, cursor
#define SCAN_B 256
__global__ void scan1_kernel(const int* __restrict__ counts, int n,
                             int* __restrict__ bsum) {
  __shared__ int lds[SCAN_B];
  int t = threadIdx.x;
  int i = blockIdx.x * SCAN_B + t;
  lds[t] = (i < n) ? counts[i] : 0;
  __syncthreads();
#pragma unroll
  for (int off = SCAN_B / 2; off; off >>= 1) {
    if (t < off) lds[t] += lds[t + off];
    __syncthreads();
  }
  if (t == 0) bsum[blockIdx.x] = lds[0];
}

__global__ void scan2_kernel(int* __restrict__ bsum, int nb) {
  __shared__ int lds[1024];
  int t = threadIdx.x;
  int v = (t < nb) ? bsum[t] : 0;
  lds[t] = v;
  __syncthreads();
  for (int off = 1; off < 1024; off <<= 1) {
    int x = lds[t];
    if (t >= off) x += lds[t - off];
    __syncthreads();
    lds[t] = x;
    __syncthreads();
  }
  if (t < nb) bsum[t] = lds[t] - v;   // exclusive block offset
}

__global__ void scan3_kernel(const int* __restrict__ counts,
                             const int* __restrict__ bsum, int n,
                             int* __restrict__ rowptr, int* __restrict__ cursor) {
  __shared__ int lds[SCAN_B];
  int t = threadIdx.x;
  int i = blockIdx.x * SCAN_B + t;
  int v = (i < n) ? counts[i] : 0;
  lds[t] = v;
  __syncthreads();
#pragma unroll
  for (int off = 1; off < SCAN_B; off <<= 1) {
    int x = lds[t];
    if (t >= off) x += lds[t - off];
    __syncthreads();
    lds[t] = x;
    __syncthreads();
  }
  if (i < n) {
    int incl = lds[t] + bsum[blockIdx.x];
    rowptr[i + 1] = incl;
    cursor[i] = incl - v;
    if (i == 0) rowptr[0] = 0;
  }
}

__global__ void scatter_kernel(const int* __restrict__ src, const int* __restrict__ dst,
                               int E, int N, int* __restrict__ cursor,
                               int* __restrict__ adj) {
  int e = blockIdx.x * blockDim.x + threadIdx.x;
  if (e >= E + N) return;
  int s, d;
  if (e < E) { s = src[e]; d = dst[e]; }
  else       { s = e - E; d = s; }
  int slot = atomicAdd(&cursor[d], 1);
  adj[slot] = s;
}

// ---------------- GraphConv ----------------
__global__ void agg_kernel(const float* __restrict__ x, const int* __restrict__ src,
                           const int* __restrict__ dst, int E, float* __restrict__ agg) {
  int e = blockIdx.x * blockDim.x + threadIdx.x;
  if (e >= E) return;
  int s = src[e], d = dst[e];
  atomicAdd(&agg[d * 2 + 0], x[s * 2 + 0]);
  atomicAdd(&agg[d * 2 + 1], x[s * 2 + 1]);
}

__global__ void graphconv_kernel(const float* __restrict__ x, const float* __restrict__ agg,
                                 const float* __restrict__ W_rel, const float* __restrict__ b_rel,
                                 const float* __restrict__ W_root,
                                 unsigned short* __restrict__ h0b, int Nn) {
  int i = blockIdx.x * blockDim.x + threadIdx.x;
  if (i >= Nn * 64) return;
  int n = i >> 6, c = i & 63;
  float a0 = agg[n * 2], a1 = agg[n * 2 + 1];
  float x0 = x[n * 2], x1 = x[n * 2 + 1];
  float v = a0 * W_rel[c] + a1 * W_rel[64 + c]
          + x0 * W_root[c] + x1 * W_root[64 + c] + b_rel[c];
  h0b[i] = f2bf(fmaxf(v, 0.f));
}

// ---------------- weight transpose+convert: W[K][N] -> Wt[N][K] bf16 -------
__global__ void wt_kernel(const float* __restrict__ W, unsigned short* __restrict__ Wt,
                          int K, int N) {
  int i = blockIdx.x * blockDim.x + threadIdx.x;
  if (i >= K * N) return;
  int n = i / K, k = i - n * K;
  Wt[i] = f2bf(W[k * N + n]);
}

// ---------------- bf16 MFMA GEMM + fused attention logits ------------------
template <int BM, int BN, int WARPS_M, int WARPS_N, int H>
__global__ __launch_bounds__(256) void mfma_gemm(const unsigned short* __restrict__ A,
    const unsigned short* __restrict__ Bt, unsigned short* __restrict__ C,
    const float* __restrict__ a_s, const float* __restrict__ a_d,
    float* __restrict__ alS, float* __restrict__ alD, int M, int N, int K) {
  __shared__ unsigned char lds[(BM + BN) * 80];
  unsigned char* As = lds;
  unsigned char* Bs = lds + BM * 80;
  int t = threadIdx.x;
  int w = t >> 6, l = t & 63;
  int wm = w / WARPS_N, wn = w % WARPS_N;
  int row0 = blockIdx.y * BM;
  int col0 = blockIdx.x * BN;
  f32x4 acc[4][4] = {};
  int slot = l >> 4, rr = l & 15;
  for (int k0 = 0; k0 < K; k0 += 32) {
    if (k0) __syncthreads();
#pragma unroll
    for (int u = 0; u < BM * 4 / 256; ++u) {
      int s = t + u * 256;
      int r = s >> 2, sl = s & 3;
      int gr = row0 + r;
      uint4 v = make_uint4(0u, 0u, 0u, 0u);
      if (gr < M) v = *reinterpret_cast<const uint4*>(A + (size_t)gr * K + k0 + sl * 8);
      *reinterpret_cast<uint4*>(As + r * 80 + sl * 16) = v;
    }
#pragma unroll
    for (int u = 0; u < BN * 4 / 256; ++u) {
      int s = t + u * 256;
      int r = s >> 2, sl = s & 3;
      uint4 v = *reinterpret_cast<const uint4*>(Bt + (size_t)(col0 + r) * K + k0 + sl * 8);
      *reinterpret_cast<uint4*>(Bs + r * 80 + sl * 16) = v;
    }
    __syncthreads();
    bf16x8 a[4], b[4];
#pragma unroll
    for (int i = 0; i < 4; ++i)
      a[i] = *reinterpret_cast<const bf16x8*>(As + (wm * 64 + i * 16 + rr) * 80 + slot * 16);
#pragma unroll
    for (int j = 0; j < 4; ++j)
      b[j] = *reinterpret_cast<const bf16x8*>(Bs + (wn * 64 + j * 16 + rr) * 80 + slot * 16);
#pragma unroll
    for (int i = 0; i < 4; ++i)
#pragma unroll
      for (int j = 0; j < 4; ++j)
        acc[i][j] = __builtin_amdgcn_mfma_f32_16x16x32_bf16(a[i], b[j], acc[i][j], 0, 0, 0);
  }
  // C write. C/D layout: col = l&15, row = (l>>4)*4 + reg
  int rb = row0 + wm * 64 + (l >> 4) * 4;
  int cb = col0 + wn * 64 + (l & 15);
#pragma unroll
  for (int i = 0; i < 4; ++i) {
#pragma unroll
    for (int r = 0; r < 4; ++r) {
      int gr = rb + i * 16 + r;
      if (gr < M) {
#pragma unroll
        for (int j = 0; j < 4; ++j)
          C[(size_t)gr * N + cb + j * 16] = f2bf(acc[i][j][r]);
      }
    }
  }
  // fused logits: this warp's head
  int hd = (col0 >> 6) + wn;
  int ch = l & 15;
  float as0 = a_s[hd * 64 + ch], as1 = a_s[hd * 64 + ch + 16];
  float as2 = a_s[hd * 64 + ch + 32], as3 = a_s[hd * 64 + ch + 48];
  float ad0 = a_d[hd * 64 + ch], ad1 = a_d[hd * 64 + ch + 16];
  float ad2 = a_d[hd * 64 + ch + 32], ad3 = a_d[hd * 64 + ch + 48];
#pragma unroll
  for (int i = 0; i < 4; ++i) {
#pragma unroll
    for (int r = 0; r < 4; ++r) {
      float ps = acc[i][0][r] * as0 + acc[i][1][r] * as1
               + acc[i][2][r] * as2 + acc[i][3][r] * as3;
      float pd = acc[i][0][r] * ad0 + acc[i][1][r] * ad1
               + acc[i][2][r] * ad2 + acc[i][3][r] * ad3;
#pragma unroll
      for (int off = 1; off < 16; off <<= 1) {
        ps += __shfl_xor(ps, off);
        pd += __shfl_xor(pd, off);
      }
      if ((l & 15) == 0) {
        int gr = rb + i * 16 + r;
        if (gr < M) {
          alS[gr * H + hd] = ps;
          alD[gr * H + hd] = pd;
        }
      }
    }
  }
}

// ---------------- GAT gather, 256 ch (4 heads), bf16 in/out ----------------
template <bool RELU>
__global__ __launch_bounds__(256) void gat_gather256(const unsigned short* __restrict__ hW,
    const float* __restrict__ alS, const float* __restrict__ alD,
    const int* __restrict__ rowptr, const int* __restrict__ adj,
    const float* __restrict__ bias, unsigned short* __restrict__ outb, int N) {
  int w = threadIdx.x >> 6, l = threadIdx.x & 63;
  int node = blockIdx.x * 4 + w;
  if (node >= N) return;
  int head = l >> 4;
  int c = l << 2;
  float ald = alD[node * 4 + head];
  int s0 = rowptr[node], s1 = rowptr[node + 1];
  float den = 0.f, a0 = 0.f, a1 = 0.f, a2 = 0.f, a3 = 0.f;
  int s = s0;
  for (; s + 4 <= s1; s += 4) {
    int i0 = adj[s + 0], i1 = adj[s + 1], i2 = adj[s + 2], i3 = adj[s + 3];
    float v0 = alS[i0 * 4 + head];
    float v1 = alS[i1 * 4 + head];
    float v2 = alS[i2 * 4 + head];
    float v3 = alS[i3 * 4 + head];
    ushort4 h0 = *reinterpret_cast<const ushort4*>(hW + (size_t)i0 * 256 + c);
    ushort4 h1 = *reinterpret_cast<const ushort4*>(hW + (size_t)i1 * 256 + c);
    ushort4 h2 = *reinterpret_cast<const ushort4*>(hW + (size_t)i2 * 256 + c);
    ushort4 h3 = *reinterpret_cast<const ushort4*>(hW + (size_t)i3 * 256 + c);
    float w0 = __expf(lrelu02(v0 + ald));
    float w1 = __expf(lrelu02(v1 + ald));
    float w2 = __expf(lrelu02(v2 + ald));
    float w3 = __expf(lrelu02(v3 + ald));
    den += (w0 + w1) + (w2 + w3);
    a0 += w0 * bf2f(h0.x) + w1 * bf2f(h1.x) + w2 * bf2f(h2.x) + w3 * bf2f(h3.x);
    a1 += w0 * bf2f(h0.y) + w1 * bf2f(h1.y) + w2 * bf2f(h2.y) + w3 * bf2f(h3.y);
    a2 += w0 * bf2f(h0.z) + w1 * bf2f(h1.z) + w2 * bf2f(h2.z) + w3 * bf2f(h3.z);
    a3 += w0 * bf2f(h0.w) + w1 * bf2f(h1.w) + w2 * bf2f(h2.w) + w3 * bf2f(h3.w);
  }
  for (; s < s1; ++s) {
    int i0 = adj[s];
    float v0 = alS[i0 * 4 + head];
    ushort4 h0 = *reinterpret_cast<const ushort4*>(hW + (size_t)i0 * 256 + c);
    float w0 = __expf(lrelu02(v0 + ald));
    den += w0;
    a0 += w0 * bf2f(h0.x);
    a1 += w0 * bf2f(h0.y);
    a2 += w0 * bf2f(h0.z);
    a3 += w0 * bf2f(h0.w);
  }
  float inv = 1.f / (den + 1e-16f);
  float o0 = a0 * inv + bias[c + 0];
  float o1 = a1 * inv + bias[c + 1];
  float o2 = a2 * inv + bias[c + 2];
  float o3 = a3 * inv + bias[c + 3];
  if (RELU) {
    o0 = fmaxf(o0, 0.f); o1 = fmaxf(o1, 0.f);
    o2 = fmaxf(o2, 0.f); o3 = fmaxf(o3, 0.f);
  }
  ushort4 ov;
  ov.x = f2bf(o0); ov.y = f2bf(o1); ov.z = f2bf(o2); ov.w = f2bf(o3);
  *reinterpret_cast<ushort4*>(outb + (size_t)node * 256 + c) = ov;
}

// ---------------- GAT gather, 64 ch (1 head), bf16 in, fp32 out ------------
template <bool RELU>
__global__ __launch_bounds__(256) void gat_gather64(const unsigned short* __restrict__ hW,
    const float* __restrict__ alS, const float* __restrict__ alD,
    const int* __restrict__ rowptr, const int* __restrict__ adj,
    const float* __restrict__ bias, float* __restrict__ out, int N) {
  int w = threadIdx.x >> 6, l = threadIdx.x & 63;
  int node = blockIdx.x * 4 + w;
  if (node >= N) return;
  int g = l >> 4;
  int c = (l & 15) << 2;
  float ald = alD[node];
  int s0 = rowptr[node], s1 = rowptr[node + 1];
  float den = 0.f, a0 = 0.f, a1 = 0.f, a2 = 0.f, a3 = 0.f;
  int s = s0 + g;
  for (; s + 4 < s1; s += 8) {
    int i0 = adj[s], i1 = adj[s + 4];
    float v0 = alS[i0], v1 = alS[i1];
    ushort4 h0 = *reinterpret_cast<const ushort4*>(hW + (size_t)i0 * 64 + c);
    ushort4 h1 = *reinterpret_cast<const ushort4*>(hW + (size_t)i1 * 64 + c);
    float w0 = __expf(lrelu02(v0 + ald));
    float w1 = __expf(lrelu02(v1 + ald));
    den += w0 + w1;
    a0 += w0 * bf2f(h0.x) + w1 * bf2f(h1.x);
    a1 += w0 * bf2f(h0.y) + w1 * bf2f(h1.y);
    a2 += w0 * bf2f(h0.z) + w1 * bf2f(h1.z);
    a3 += w0 * bf2f(h0.w) + w1 * bf2f(h1.w);
  }
  if (s < s1) {
    int i0 = adj[s];
    float v0 = alS[i0];
    ushort4 h0 = *reinterpret_cast<const ushort4*>(hW + (size_t)i0 * 64 + c);
    float w0 = __expf(lrelu02(v0 + ald));
    den += w0;
    a0 += w0 * bf2f(h0.x);
    a1 += w0 * bf2f(h0.y);
    a2 += w0 * bf2f(h0.z);
    a3 += w0 * bf2f(h0.w);
  }
#pragma unroll
  for (int off = 16; off <= 32; off <<= 1) {
    den += __shfl_xor(den, off);
    a0 += __shfl_xor(a0, off);
    a1 += __shfl_xor(a1, off);
    a2 += __shfl_xor(a2, off);
    a3 += __shfl_xor(a3, off);
  }
  if (g == 0) {
    float inv = 1.f / (den + 1e-16f);
    float o0 = a0 * inv + bias[c + 0];
    float o1 = a1 * inv + bias[c + 1];
    float o2 = a2 * inv + bias[c + 2];
    float o3 = a3 * inv + bias[c + 3];
    if (RELU) {
      o0 = fmaxf(o0, 0.f); o1 = fmaxf(o1, 0.f);
      o2 = fmaxf(o2, 0.f); o3 = fmaxf(o3, 0.f);
    }
    *reinterpret_cast<float4*>(out + (size_t)node * 64 + c) = make_float4(o0, o1, o2, o3);
  }
}

// ---------------------------------------------------------------------------
extern "C" void kernel_launch(void* const* d_in, const int* in_sizes, int n_in,
                              void* d_out, int out_size, void* d_ws, size_t ws_size,
                              hipStream_t stream) {
  const float* x      = (const float*)d_in[0];
  const float* W_rel  = (const float*)d_in[1];
  const float* b_rel  = (const float*)d_in[2];
  const float* W_root = (const float*)d_in[3];
  const float* W1     = (const float*)d_in[4];
  const float* a_s1   = (const float*)d_in[5];
  const float* a_d1   = (const float*)d_in[6];
  const float* b1     = (const float*)d_in[7];
  const float* W2     = (const float*)d_in[8];
  const float* a_s2   = (const float*)d_in[9];
  const float* a_d2   = (const float*)d_in[10];
  const float* b2     = (const float*)d_in[11];
  const float* W3     = (const float*)d_in[12];
  const float* a_s3   = (const float*)d_in[13];
  const float* a_d3   = (const float*)d_in[14];
  const float* b3     = (const float*)d_in[15];
  const int*   ei     = (const int*)d_in[16];

  int N = in_sizes[0] / 2;
  int E = in_sizes[16] / 2;
  const int* srcp = ei;
  const int* dstp = ei + E;

  // workspace layout (~75 MB), bf16 sections 16B-aligned
  unsigned short* h0b  = (unsigned short*)d_ws;            // N*64 bf16
  unsigned short* bufX = h0b + (size_t)N * 64;             // N*256 bf16
  unsigned short* bufY = bufX + (size_t)N * 256;           // N*256 bf16
  unsigned short* bufZ = bufY + (size_t)N * 256;           // N*64 bf16
  unsigned short* Wt1  = bufZ + (size_t)N * 64;            // 256*64
  unsigned short* Wt2  = Wt1 + 256 * 64;                   // 256*256
  unsigned short* Wt3  = Wt2 + 256 * 256;                  // 64*256
  float* agg  = (float*)(Wt3 + 64 * 256);                  // N*2
  float* alS  = agg + (size_t)N * 2;                       // N*4
  float* alD  = alS + (size_t)N * 4;                       // N*4
  int* adj    = (int*)(alD + (size_t)N * 4);               // E+N
  int* rowptr = adj + (E + N);                             // N+1
  int* counts = rowptr + (N + 1);                          // N
  int* cursor = counts + N;                                // N
  int* bsum   = cursor + N;                                // ceil(N/256)

  hipMemsetAsync(agg, 0, (size_t)N * 2 * sizeof(float), stream);
  hipMemsetAsync(counts, 0, (size_t)N * sizeof(int), stream);

  int ESL = E + N;
  int tb = 256;
  int nb = (N + SCAN_B - 1) / SCAN_B;

  // CSR build (shared by all 3 GAT layers)
  count_kernel<<<(ESL + tb - 1) / tb, tb, 0, stream>>>(dstp, E, N, counts);
  scan1_kernel<<<nb, SCAN_B, 0, stream>>>(counts, N, bsum);
  scan2_kernel<<<1, 1024, 0, stream>>>(bsum, nb);
  scan3_kernel<<<nb, SCAN_B, 0, stream>>>(counts, bsum, N, rowptr, cursor);
  scatter_kernel<<<(ESL + tb - 1) / tb, tb, 0, stream>>>(srcp, dstp, E, N, cursor, adj);

  // weight transpose/convert (tiny)
  wt_kernel<<<(64 * 256 + tb - 1) / tb, tb, 0, stream>>>(W1, Wt1, 64, 256);
  wt_kernel<<<(256 * 256 + tb - 1) / tb, tb, 0, stream>>>(W2, Wt2, 256, 256);
  wt_kernel<<<(256 * 64 + tb - 1) / tb, tb, 0, stream>>>(W3, Wt3, 256, 64);

  // GraphConv (real edges only) + ReLU -> bf16
  agg_kernel<<<(E + tb - 1) / tb, tb, 0, stream>>>(x, srcp, dstp, E, agg);
  graphconv_kernel<<<(N * 64 + tb - 1) / tb, tb, 0, stream>>>(x, agg, W_rel, b_rel, W_root, h0b, N);

  dim3 gA(256 / 128, (N + 127) / 128);   // layers 1,2: N=256 -> 2 col tiles
  dim3 gB(1, (N + 255) / 256);           // layer 3: N=64
  int gN4 = (N + 3) / 4;

  // GAT layer 1: 64 -> 4x64, relu
  mfma_gemm<128, 128, 2, 2, 4><<<gA, 256, 0, stream>>>(h0b, Wt1, bufX, a_s1, a_d1, alS, alD, N, 256, 64);
  gat_gather256<true><<<gN4, 256, 0, stream>>>(bufX, alS, alD, rowptr, adj, b1, bufY, N);

  // GAT layer 2: 256 -> 4x64, relu
  mfma_gemm<128, 128, 2, 2, 4><<<gA, 256, 0, stream>>>(bufY, Wt2, bufX, a_s2, a_d2, alS, alD, N, 256, 256);
  gat_gather256<true><<<gN4, 256, 0, stream>>>(bufX, alS, alD, rowptr, adj, b2, bufY, N);

  // GAT layer 3: 256 -> 64, heads=1, no relu
  mfma_gemm<256, 64, 4, 1, 1><<<gB, 256, 0, stream>>>(bufY, Wt3, bufZ, a_s3, a_d3, alS, alD, N, 64, 256);
  gat_gather64<false><<<gN4, 256, 0, stream>>>(bufZ, alS, alD, rowptr, adj, b3, (float*)d_out, N);
}

// Round 7
// 351.256 us; speedup vs baseline: 2.9410x; 1.2236x over previous
//
#include <hip/hip_runtime.h>
#include <hip/hip_bf16.h>
#include <cstdint>

// ---------------------------------------------------------------------------
// DynamicGAT: GraphConv(2->64) + GAT(64->4x64) + GAT(256->4x64) + GAT(256->64)
// R6: agg_kernel (1.6M fp32 atomics, 86us, both pipes idle) replaced by
// CSR-gather fused into GraphConv: agg[i] = sum_{row(i)} x[j] - x[i]
// (self-loop subtracted). Wave per node, shfl butterfly reduce.
// ---------------------------------------------------------------------------

typedef __attribute__((ext_vector_type(8))) short bf16x8;
typedef __attribute__((ext_vector_type(4))) float f32x4;

__device__ inline unsigned short f2bf(float f) {
  union { float f; uint32_t u; } x; x.f = f;
  uint32_t r = x.u + 0x7FFF + ((x.u >> 16) & 1);   // RNE
  return (unsigned short)(r >> 16);
}
__device__ inline float bf2f(unsigned short u) {
  union { uint32_t u; float f; } x; x.u = ((uint32_t)u) << 16; return x.f;
}
__device__ inline float lrelu02(float v) { return v > 0.f ? v : 0.2f * v; }

// ---------------- CSR build ----------------
__global__ void count_kernel(const int* __restrict__ dst, int E, int N,
                             int* __restrict__ counts) {
  int e = blockIdx.x * blockDim.x + threadIdx.x;
  if (e >= E + N) return;
  int d = (e < E) ? dst[e] : (e - E);   // self loops appended
  atomicAdd(&counts[d], 1);
}

// 3-pass device-wide exclusive scan of counts[0..n) -> rowptr, cursor
#define SCAN_B 256
__global__ void scan1_kernel(const int* __restrict__ counts, int n,
                             int* __restrict__ bsum) {
  __shared__ int lds[SCAN_B];
  int t = threadIdx.x;
  int i = blockIdx.x * SCAN_B + t;
  lds[t] = (i < n) ? counts[i] : 0;
  __syncthreads();
#pragma unroll
  for (int off = SCAN_B / 2; off; off >>= 1) {
    if (t < off) lds[t] += lds[t + off];
    __syncthreads();
  }
  if (t == 0) bsum[blockIdx.x] = lds[0];
}

__global__ void scan2_kernel(int* __restrict__ bsum, int nb) {
  __shared__ int lds[1024];
  int t = threadIdx.x;
  int v = (t < nb) ? bsum[t] : 0;
  lds[t] = v;
  __syncthreads();
  for (int off = 1; off < 1024; off <<= 1) {
    int x = lds[t];
    if (t >= off) x += lds[t - off];
    __syncthreads();
    lds[t] = x;
    __syncthreads();
  }
  if (t < nb) bsum[t] = lds[t] - v;   // exclusive block offset
}

__global__ void scan3_kernel(const int* __restrict__ counts,
                             const int* __restrict__ bsum, int n,
                             int* __restrict__ rowptr, int* __restrict__ cursor) {
  __shared__ int lds[SCAN_B];
  int t = threadIdx.x;
  int i = blockIdx.x * SCAN_B + t;
  int v = (i < n) ? counts[i] : 0;
  lds[t] = v;
  __syncthreads();
#pragma unroll
  for (int off = 1; off < SCAN_B; off <<= 1) {
    int x = lds[t];
    if (t >= off) x += lds[t - off];
    __syncthreads();
    lds[t] = x;
    __syncthreads();
  }
  if (i < n) {
    int incl = lds[t] + bsum[blockIdx.x];
    rowptr[i + 1] = incl;
    cursor[i] = incl - v;
    if (i == 0) rowptr[0] = 0;
  }
}

__global__ void scatter_kernel(const int* __restrict__ src, const int* __restrict__ dst,
                               int E, int N, int* __restrict__ cursor,
                               int* __restrict__ adj) {
  int e = blockIdx.x * blockDim.x + threadIdx.x;
  if (e >= E + N) return;
  int s, d;
  if (e < E) { s = src[e]; d = dst[e]; }
  else       { s = e - E; d = s; }
  int slot = atomicAdd(&cursor[d], 1);
  adj[slot] = s;
}

// ---------------- GraphConv via CSR gather (fused) ----------------
// wave per node; lanes stride row edges loading x[j] (float2), butterfly
// reduce; self-loop contribution subtracted; lane c computes channel c.
__global__ __launch_bounds__(256) void graphconv_csr(const float* __restrict__ x,
    const int* __restrict__ rowptr, const int* __restrict__ adj,
    const float* __restrict__ W_rel, const float* __restrict__ b_rel,
    const float* __restrict__ W_root, unsigned short* __restrict__ h0b, int N) {
  int w = threadIdx.x >> 6, l = threadIdx.x & 63;
  int node = blockIdx.x * 4 + w;
  if (node >= N) return;
  int s0 = rowptr[node], s1 = rowptr[node + 1];
  float a0 = 0.f, a1 = 0.f;
  for (int s = s0 + l; s < s1; s += 64) {
    int j = adj[s];
    float2 xv = *reinterpret_cast<const float2*>(x + (size_t)j * 2);
    a0 += xv.x; a1 += xv.y;
  }
#pragma unroll
  for (int off = 1; off < 64; off <<= 1) {
    a0 += __shfl_xor(a0, off);
    a1 += __shfl_xor(a1, off);
  }
  float2 xi = *reinterpret_cast<const float2*>(x + (size_t)node * 2);
  a0 -= xi.x; a1 -= xi.y;   // remove appended self loop (GraphConv: real edges)
  int c = l;
  float v = a0 * W_rel[c] + a1 * W_rel[64 + c]
          + xi.x * W_root[c] + xi.y * W_root[64 + c] + b_rel[c];
  h0b[(size_t)node * 64 + c] = f2bf(fmaxf(v, 0.f));
}

// ---------------- weight transpose+convert: W[K][N] -> Wt[N][K] bf16 -------
__global__ void wt_kernel(const float* __restrict__ W, unsigned short* __restrict__ Wt,
                          int K, int N) {
  int i = blockIdx.x * blockDim.x + threadIdx.x;
  if (i >= K * N) return;
  int n = i / K, k = i - n * K;
  Wt[i] = f2bf(W[k * N + n]);
}

// ---------------- bf16 MFMA GEMM + fused attention logits ------------------
template <int BM, int BN, int WARPS_M, int WARPS_N, int H>
__global__ __launch_bounds__(256) void mfma_gemm(const unsigned short* __restrict__ A,
    const unsigned short* __restrict__ Bt, unsigned short* __restrict__ C,
    const float* __restrict__ a_s, const float* __restrict__ a_d,
    float* __restrict__ alS, float* __restrict__ alD, int M, int N, int K) {
  __shared__ unsigned char lds[(BM + BN) * 80];
  unsigned char* As = lds;
  unsigned char* Bs = lds + BM * 80;
  int t = threadIdx.x;
  int w = t >> 6, l = t & 63;
  int wm = w / WARPS_N, wn = w % WARPS_N;
  int row0 = blockIdx.y * BM;
  int col0 = blockIdx.x * BN;
  f32x4 acc[4][4] = {};
  int slot = l >> 4, rr = l & 15;
  for (int k0 = 0; k0 < K; k0 += 32) {
    if (k0) __syncthreads();
#pragma unroll
    for (int u = 0; u < BM * 4 / 256; ++u) {
      int s = t + u * 256;
      int r = s >> 2, sl = s & 3;
      int gr = row0 + r;
      uint4 v = make_uint4(0u, 0u, 0u, 0u);
      if (gr < M) v = *reinterpret_cast<const uint4*>(A + (size_t)gr * K + k0 + sl * 8);
      *reinterpret_cast<uint4*>(As + r * 80 + sl * 16) = v;
    }
#pragma unroll
    for (int u = 0; u < BN * 4 / 256; ++u) {
      int s = t + u * 256;
      int r = s >> 2, sl = s & 3;
      uint4 v = *reinterpret_cast<const uint4*>(Bt + (size_t)(col0 + r) * K + k0 + sl * 8);
      *reinterpret_cast<uint4*>(Bs + r * 80 + sl * 16) = v;
    }
    __syncthreads();
    bf16x8 a[4], b[4];
#pragma unroll
    for (int i = 0; i < 4; ++i)
      a[i] = *reinterpret_cast<const bf16x8*>(As + (wm * 64 + i * 16 + rr) * 80 + slot * 16);
#pragma unroll
    for (int j = 0; j < 4; ++j)
      b[j] = *reinterpret_cast<const bf16x8*>(Bs + (wn * 64 + j * 16 + rr) * 80 + slot * 16);
#pragma unroll
    for (int i = 0; i < 4; ++i)
#pragma unroll
      for (int j = 0; j < 4; ++j)
        acc[i][j] = __builtin_amdgcn_mfma_f32_16x16x32_bf16(a[i], b[j], acc[i][j], 0, 0, 0);
  }
  // C write. C/D layout: col = l&15, row = (l>>4)*4 + reg
  int rb = row0 + wm * 64 + (l >> 4) * 4;
  int cb = col0 + wn * 64 + (l & 15);
#pragma unroll
  for (int i = 0; i < 4; ++i) {
#pragma unroll
    for (int r = 0; r < 4; ++r) {
      int gr = rb + i * 16 + r;
      if (gr < M) {
#pragma unroll
        for (int j = 0; j < 4; ++j)
          C[(size_t)gr * N + cb + j * 16] = f2bf(acc[i][j][r]);
      }
    }
  }
  // fused logits: this warp's head
  int hd = (col0 >> 6) + wn;
  int ch = l & 15;
  float as0 = a_s[hd * 64 + ch], as1 = a_s[hd * 64 + ch + 16];
  float as2 = a_s[hd * 64 + ch + 32], as3 = a_s[hd * 64 + ch + 48];
  float ad0 = a_d[hd * 64 + ch], ad1 = a_d[hd * 64 + ch + 16];
  float ad2 = a_d[hd * 64 + ch + 32], ad3 = a_d[hd * 64 + ch + 48];
#pragma unroll
  for (int i = 0; i < 4; ++i) {
#pragma unroll
    for (int r = 0; r < 4; ++r) {
      float ps = acc[i][0][r] * as0 + acc[i][1][r] * as1
               + acc[i][2][r] * as2 + acc[i][3][r] * as3;
      float pd = acc[i][0][r] * ad0 + acc[i][1][r] * ad1
               + acc[i][2][r] * ad2 + acc[i][3][r] * ad3;
#pragma unroll
      for (int off = 1; off < 16; off <<= 1) {
        ps += __shfl_xor(ps, off);
        pd += __shfl_xor(pd, off);
      }
      if ((l & 15) == 0) {
        int gr = rb + i * 16 + r;
        if (gr < M) {
          alS[gr * H + hd] = ps;
          alD[gr * H + hd] = pd;
        }
      }
    }
  }
}

// ---------------- GAT gather, 256 ch (4 heads), bf16 in/out ----------------
template <bool RELU>
__global__ __launch_bounds__(256) void gat_gather256(const unsigned short* __restrict__ hW,
    const float* __restrict__ alS, const float* __restrict__ alD,
    const int* __restrict__ rowptr, const int* __restrict__ adj,
    const float* __restrict__ bias, unsigned short* __restrict__ outb, int N) {
  int w = threadIdx.x >> 6, l = threadIdx.x & 63;
  int node = blockIdx.x * 4 + w;
  if (node >= N) return;
  int head = l >> 4;
  int c = l << 2;
  float ald = alD[node * 4 + head];
  int s0 = rowptr[node], s1 = rowptr[node + 1];
  float den = 0.f, a0 = 0.f, a1 = 0.f, a2 = 0.f, a3 = 0.f;
  int s = s0;
  for (; s + 4 <= s1; s += 4) {
    int i0 = adj[s + 0], i1 = adj[s + 1], i2 = adj[s + 2], i3 = adj[s + 3];
    float v0 = alS[i0 * 4 + head];
    float v1 = alS[i1 * 4 + head];
    float v2 = alS[i2 * 4 + head];
    float v3 = alS[i3 * 4 + head];
    ushort4 h0 = *reinterpret_cast<const ushort4*>(hW + (size_t)i0 * 256 + c);
    ushort4 h1 = *reinterpret_cast<const ushort4*>(hW + (size_t)i1 * 256 + c);
    ushort4 h2 = *reinterpret_cast<const ushort4*>(hW + (size_t)i2 * 256 + c);
    ushort4 h3 = *reinterpret_cast<const ushort4*>(hW + (size_t)i3 * 256 + c);
    float w0 = __expf(lrelu02(v0 + ald));
    float w1 = __expf(lrelu02(v1 + ald));
    float w2 = __expf(lrelu02(v2 + ald));
    float w3 = __expf(lrelu02(v3 + ald));
    den += (w0 + w1) + (w2 + w3);
    a0 += w0 * bf2f(h0.x) + w1 * bf2f(h1.x) + w2 * bf2f(h2.x) + w3 * bf2f(h3.x);
    a1 += w0 * bf2f(h0.y) + w1 * bf2f(h1.y) + w2 * bf2f(h2.y) + w3 * bf2f(h3.y);
    a2 += w0 * bf2f(h0.z) + w1 * bf2f(h1.z) + w2 * bf2f(h2.z) + w3 * bf2f(h3.z);
    a3 += w0 * bf2f(h0.w) + w1 * bf2f(h1.w) + w2 * bf2f(h2.w) + w3 * bf2f(h3.w);
  }
  for (; s < s1; ++s) {
    int i0 = adj[s];
    float v0 = alS[i0 * 4 + head];
    ushort4 h0 = *reinterpret_cast<const ushort4*>(hW + (size_t)i0 * 256 + c);
    float w0 = __expf(lrelu02(v0 + ald));
    den += w0;
    a0 += w0 * bf2f(h0.x);
    a1 += w0 * bf2f(h0.y);
    a2 += w0 * bf2f(h0.z);
    a3 += w0 * bf2f(h0.w);
  }
  float inv = 1.f / (den + 1e-16f);
  float o0 = a0 * inv + bias[c + 0];
  float o1 = a1 * inv + bias[c + 1];
  float o2 = a2 * inv + bias[c + 2];
  float o3 = a3 * inv + bias[c + 3];
  if (RELU) {
    o0 = fmaxf(o0, 0.f); o1 = fmaxf(o1, 0.f);
    o2 = fmaxf(o2, 0.f); o3 = fmaxf(o3, 0.f);
  }
  ushort4 ov;
  ov.x = f2bf(o0); ov.y = f2bf(o1); ov.z = f2bf(o2); ov.w = f2bf(o3);
  *reinterpret_cast<ushort4*>(outb + (size_t)node * 256 + c) = ov;
}

// ---------------- GAT gather, 64 ch (1 head), bf16 in, fp32 out ------------
template <bool RELU>
__global__ __launch_bounds__(256) void gat_gather64(const unsigned short* __restrict__ hW,
    const float* __restrict__ alS, const float* __restrict__ alD,
    const int* __restrict__ rowptr, const int* __restrict__ adj,
    const float* __restrict__ bias, float* __restrict__ out, int N) {
  int w = threadIdx.x >> 6, l = threadIdx.x & 63;
  int node = blockIdx.x * 4 + w;
  if (node >= N) return;
  int g = l >> 4;
  int c = (l & 15) << 2;
  float ald = alD[node];
  int s0 = rowptr[node], s1 = rowptr[node + 1];
  float den = 0.f, a0 = 0.f, a1 = 0.f, a2 = 0.f, a3 = 0.f;
  int s = s0 + g;
  for (; s + 4 < s1; s += 8) {
    int i0 = adj[s], i1 = adj[s + 4];
    float v0 = alS[i0], v1 = alS[i1];
    ushort4 h0 = *reinterpret_cast<const ushort4*>(hW + (size_t)i0 * 64 + c);
    ushort4 h1 = *reinterpret_cast<const ushort4*>(hW + (size_t)i1 * 64 + c);
    float w0 = __expf(lrelu02(v0 + ald));
    float w1 = __expf(lrelu02(v1 + ald));
    den += w0 + w1;
    a0 += w0 * bf2f(h0.x) + w1 * bf2f(h1.x);
    a1 += w0 * bf2f(h0.y) + w1 * bf2f(h1.y);
    a2 += w0 * bf2f(h0.z) + w1 * bf2f(h1.z);
    a3 += w0 * bf2f(h0.w) + w1 * bf2f(h1.w);
  }
  if (s < s1) {
    int i0 = adj[s];
    float v0 = alS[i0];
    ushort4 h0 = *reinterpret_cast<const ushort4*>(hW + (size_t)i0 * 64 + c);
    float w0 = __expf(lrelu02(v0 + ald));
    den += w0;
    a0 += w0 * bf2f(h0.x);
    a1 += w0 * bf2f(h0.y);
    a2 += w0 * bf2f(h0.z);
    a3 += w0 * bf2f(h0.w);
  }
#pragma unroll
  for (int off = 16; off <= 32; off <<= 1) {
    den += __shfl_xor(den, off);
    a0 += __shfl_xor(a0, off);
    a1 += __shfl_xor(a1, off);
    a2 += __shfl_xor(a2, off);
    a3 += __shfl_xor(a3, off);
  }
  if (g == 0) {
    float inv = 1.f / (den + 1e-16f);
    float o0 = a0 * inv + bias[c + 0];
    float o1 = a1 * inv + bias[c + 1];
    float o2 = a2 * inv + bias[c + 2];
    float o3 = a3 * inv + bias[c + 3];
    if (RELU) {
      o0 = fmaxf(o0, 0.f); o1 = fmaxf(o1, 0.f);
      o2 = fmaxf(o2, 0.f); o3 = fmaxf(o3, 0.f);
    }
    *reinterpret_cast<float4*>(out + (size_t)node * 64 + c) = make_float4(o0, o1, o2, o3);
  }
}

// ---------------------------------------------------------------------------
extern "C" void kernel_launch(void* const* d_in, const int* in_sizes, int n_in,
                              void* d_out, int out_size, void* d_ws, size_t ws_size,
                              hipStream_t stream) {
  const float* x      = (const float*)d_in[0];
  const float* W_rel  = (const float*)d_in[1];
  const float* b_rel  = (const float*)d_in[2];
  const float* W_root = (const float*)d_in[3];
  const float* W1     = (const float*)d_in[4];
  const float* a_s1   = (const float*)d_in[5];
  const float* a_d1   = (const float*)d_in[6];
  const float* b1     = (const float*)d_in[7];
  const float* W2     = (const float*)d_in[8];
  const float* a_s2   = (const float*)d_in[9];
  const float* a_d2   = (const float*)d_in[10];
  const float* b2     = (const float*)d_in[11];
  const float* W3     = (const float*)d_in[12];
  const float* a_s3   = (const float*)d_in[13];
  const float* a_d3   = (const float*)d_in[14];
  const float* b3     = (const float*)d_in[15];
  const int*   ei     = (const int*)d_in[16];

  int N = in_sizes[0] / 2;
  int E = in_sizes[16] / 2;
  const int* srcp = ei;
  const int* dstp = ei + E;

  // workspace layout (~75 MB), bf16 sections 16B-aligned
  unsigned short* h0b  = (unsigned short*)d_ws;            // N*64 bf16
  unsigned short* bufX = h0b + (size_t)N * 64;             // N*256 bf16
  unsigned short* bufY = bufX + (size_t)N * 256;           // N*256 bf16
  unsigned short* bufZ = bufY + (size_t)N * 256;           // N*64 bf16
  unsigned short* Wt1  = bufZ + (size_t)N * 64;            // 256*64
  unsigned short* Wt2  = Wt1 + 256 * 64;                   // 256*256
  unsigned short* Wt3  = Wt2 + 256 * 256;                  // 64*256
  float* alS  = (float*)(Wt3 + 64 * 256);                  // N*4
  float* alD  = alS + (size_t)N * 4;                       // N*4
  int* adj    = (int*)(alD + (size_t)N * 4);               // E+N
  int* rowptr = adj + (E + N);                             // N+1
  int* counts = rowptr + (N + 1);                          // N
  int* cursor = counts + N;                                // N
  int* bsum   = cursor + N;                                // ceil(N/256)

  hipMemsetAsync(counts, 0, (size_t)N * sizeof(int), stream);

  int ESL = E + N;
  int tb = 256;
  int nb = (N + SCAN_B - 1) / SCAN_B;
  int gN4 = (N + 3) / 4;

  // CSR build (shared by GraphConv + all 3 GAT layers)
  count_kernel<<<(ESL + tb - 1) / tb, tb, 0, stream>>>(dstp, E, N, counts);
  scan1_kernel<<<nb, SCAN_B, 0, stream>>>(counts, N, bsum);
  scan2_kernel<<<1, 1024, 0, stream>>>(bsum, nb);
  scan3_kernel<<<nb, SCAN_B, 0, stream>>>(counts, bsum, N, rowptr, cursor);
  scatter_kernel<<<(ESL + tb - 1) / tb, tb, 0, stream>>>(srcp, dstp, E, N, cursor, adj);

  // weight transpose/convert (tiny)
  wt_kernel<<<(64 * 256 + tb - 1) / tb, tb, 0, stream>>>(W1, Wt1, 64, 256);
  wt_kernel<<<(256 * 256 + tb - 1) / tb, tb, 0, stream>>>(W2, Wt2, 256, 256);
  wt_kernel<<<(256 * 64 + tb - 1) / tb, tb, 0, stream>>>(W3, Wt3, 256, 64);

  // GraphConv via CSR gather (self-loop subtracted) + ReLU -> bf16
  graphconv_csr<<<gN4, 256, 0, stream>>>(x, rowptr, adj, W_rel, b_rel, W_root, h0b, N);

  dim3 gA(256 / 128, (N + 127) / 128);   // layers 1,2: N=256 -> 2 col tiles
  dim3 gB(1, (N + 255) / 256);           // layer 3: N=64

  // GAT layer 1: 64 -> 4x64, relu
  mfma_gemm<128, 128, 2, 2, 4><<<gA, 256, 0, stream>>>(h0b, Wt1, bufX, a_s1, a_d1, alS, alD, N, 256, 64);
  gat_gather256<true><<<gN4, 256, 0, stream>>>(bufX, alS, alD, rowptr, adj, b1, bufY, N);

  // GAT layer 2: 256 -> 4x64, relu
  mfma_gemm<128, 128, 2, 2, 4><<<gA, 256, 0, stream>>>(bufY, Wt2, bufX, a_s2, a_d2, alS, alD, N, 256, 256);
  gat_gather256<true><<<gN4, 256, 0, stream>>>(bufX, alS, alD, rowptr, adj, b2, bufY, N);

  // GAT layer 3: 256 -> 64, heads=1, no relu
  mfma_gemm<256, 64, 4, 1, 1><<<gB, 256, 0, stream>>>(bufY, Wt3, bufZ, a_s3, a_d3, alS, alD, N, 64, 256);
  gat_gather64<false><<<gN4, 256, 0, stream>>>(bufZ, alS, alD, rowptr, adj, b3, (float*)d_out, N);
}